// Round 2
// baseline (5648.671 us; speedup 1.0000x reference)
//
#include <hip/hip_runtime.h>

#define D_MODEL 256
#define D_INNER 1024
#define NST     16
#define SEQ     2048

// ---------------- RMSNorm: one block (256 thr) per row -------------------
__global__ __launch_bounds__(256) void rmsnorm_k(const float* __restrict__ x,
                                                 const float* __restrict__ w,
                                                 float* __restrict__ xn) {
    int row = blockIdx.x, t = threadIdx.x;
    float v = x[(size_t)row * D_MODEL + t];
    float s = v * v;
    #pragma unroll
    for (int o = 32; o; o >>= 1) s += __shfl_xor(s, o, 64);
    __shared__ float red[4];
    if ((t & 63) == 0) red[t >> 6] = s;
    __syncthreads();
    float tot = red[0] + red[1] + red[2] + red[3];
    float scale = rsqrtf(tot * (1.0f / D_MODEL) + 1e-5f);
    xn[(size_t)row * D_MODEL + t] = v * scale * w[t];
}

// ---------------- fp32 GEMM: C[M,N] = A[M,K] * W[N,K]^T ------------------
// 64x64 tile, 256 threads, 4x4 per thread. RES=1: += res, write C+coff.
template <int RES>
__global__ __launch_bounds__(256) void gemm_f32(const float* __restrict__ A,
                                                const float* __restrict__ W,
                                                float* __restrict__ C,
                                                const float* __restrict__ res,
                                                int M, int N, int K,
                                                int ldc, int coff, int ldres) {
    __shared__ float As[16][68];
    __shared__ float Ws[16][68];
    const int m0 = blockIdx.x * 64, n0 = blockIdx.y * 64;
    const int t = threadIdx.x;
    const int lr = t >> 2, lk = (t & 3) * 4;     // staging: row 0..63, k 0/4/8/12
    const int tm = (t & 15) * 4, tn = (t >> 4) * 4;
    float acc[4][4] = {};

    for (int k0 = 0; k0 < K; k0 += 16) {
        float4 av = *(const float4*)(A + (size_t)(m0 + lr) * K + k0 + lk);
        float4 wv = make_float4(0.f, 0.f, 0.f, 0.f);
        if (n0 + lr < N)
            wv = *(const float4*)(W + (size_t)(n0 + lr) * K + k0 + lk);
        As[lk + 0][lr] = av.x; As[lk + 1][lr] = av.y;
        As[lk + 2][lr] = av.z; As[lk + 3][lr] = av.w;
        Ws[lk + 0][lr] = wv.x; Ws[lk + 1][lr] = wv.y;
        Ws[lk + 2][lr] = wv.z; Ws[lk + 3][lr] = wv.w;
        __syncthreads();
        #pragma unroll
        for (int k = 0; k < 16; k++) {
            float a4[4], b4[4];
            *(float4*)a4 = *(const float4*)(&As[k][tm]);
            *(float4*)b4 = *(const float4*)(&Ws[k][tn]);
            #pragma unroll
            for (int i = 0; i < 4; i++)
                #pragma unroll
                for (int j = 0; j < 4; j++)
                    acc[i][j] += a4[i] * b4[j];
        }
        __syncthreads();
    }

    #pragma unroll
    for (int i = 0; i < 4; i++) {
        int mrow = m0 + tm + i;
        #pragma unroll
        for (int j = 0; j < 4; j++) {
            int nc = n0 + tn + j;
            if (nc < N) {
                float v = acc[i][j];
                if (RES) v += res[(size_t)mrow * ldres + nc];
                C[(size_t)mrow * ldc + coff + nc] = v;
            }
        }
    }
}

// ---------------- depthwise causal conv (4 taps) + SiLU ------------------
// dir 0: out[l] = sum_j w[j]*xi[l-3+j] ; dir 1 (time-reversed equivalent):
// out[l] = sum_j w[j]*xi[l+3-j]
__global__ __launch_bounds__(256) void conv_silu_k(const float* __restrict__ xi,
                                                   int ldx,
                                                   const float* __restrict__ cw,
                                                   const float* __restrict__ cb,
                                                   float* __restrict__ xc, int dir) {
    int idx = blockIdx.x * 256 + threadIdx.x;   // over R*D_INNER
    int d = idx & (D_INNER - 1);
    int bl = idx >> 10;
    int l = bl & (SEQ - 1);
    float acc = cb[d];
    #pragma unroll
    for (int j = 0; j < 4; j++) {
        int lo = (dir == 0) ? (l - 3 + j) : (l + 3 - j);
        if (lo >= 0 && lo < SEQ)
            acc += cw[d * 4 + j] * xi[(size_t)(bl - l + lo) * ldx + d];
    }
    float s = acc / (1.0f + expf(-acc));
    xc[(size_t)bl * D_INNER + d] = s;
}

// ---------------- fused selective scan (fp32) ----------------------------
// thread = (d,n): lane n=tid&15 holds h[d][n]; block covers 16 d values.
// y written in-place over xc (same (row,d) element, read-before-write).
__global__ __launch_bounds__(256) void scan_k(float* __restrict__ xcy,
                                              const float* __restrict__ dbl,
                                              const float* __restrict__ xz,
                                              const float* __restrict__ dtw,
                                              const float* __restrict__ dtb,
                                              const float* __restrict__ Alog,
                                              const float* __restrict__ Dp,
                                              int dir) {
    int t = threadIdx.x;
    int n = t & 15, dl = t >> 4;
    int b = blockIdx.x >> 6;                    // local batch index
    int d = (blockIdx.x & 63) * 16 + dl;

    float A   = -expf(Alog[d * NST + n]);
    float wdt = dtw[d * NST + n];
    float dtb_d = dtb[d];
    float Dd  = Dp[d];
    float h = 0.0f;

    for (int s = 0; s < SEQ; s++) {
        int l = (dir == 0) ? s : (SEQ - 1 - s);
        size_t row = (size_t)b * SEQ + l;
        const float* dr = dbl + row * 48;
        float dlow = dr[n];
        float Bn   = dr[16 + n];
        float Cn   = dr[32 + n];
        float u    = xcy[row * D_INNER + d];

        float part = dlow * wdt;
        part += __shfl_xor(part, 1, 64);
        part += __shfl_xor(part, 2, 64);
        part += __shfl_xor(part, 4, 64);
        part += __shfl_xor(part, 8, 64);
        float sp = part + dtb_d;
        float dt = (sp > 20.0f) ? sp : log1pf(expf(sp));

        float dA = expf(dt * A);
        h = h * dA + (dt * u) * Bn;

        float p = h * Cn;
        p += __shfl_xor(p, 1, 64);
        p += __shfl_xor(p, 2, 64);
        p += __shfl_xor(p, 4, 64);
        p += __shfl_xor(p, 8, 64);

        if (n == 0) {
            float z = xz[row * (2 * D_INNER) + D_INNER + d];
            float g = z / (1.0f + expf(-z));
            xcy[row * D_INNER + d] = (p + u * Dd) * g;
        }
    }
}

// ---------------- host launch --------------------------------------------
extern "C" void kernel_launch(void* const* d_in, const int* in_sizes, int n_in,
                              void* d_out, int out_size, void* d_ws, size_t ws_size,
                              hipStream_t stream) {
    const float* input = (const float*)d_in[0];
    float* out = (float*)d_out;

    // per-batch fp32 scratch: xn 2048*256 + xz 2048*2048 + xcy 2048*1024 + dbl 2048*48
    const size_t perb = (size_t)2048 * (256 + 2048 + 1024 + 48) * 4;  // 27,656,192 B
    int nb = 8;
    while (nb > 1 && (size_t)nb * perb > ws_size) nb >>= 1;
    const int R = nb * SEQ;

    float* xn  = (float*)d_ws;
    float* xz  = xn  + (size_t)R * D_MODEL;
    float* xcy = xz  + (size_t)R * 2 * D_INNER;
    float* dbl = xcy + (size_t)R * D_INNER;

    for (int dir = 0; dir < 2; dir++) {
        int o = 1 + dir * 10;
        const float* nw   = (const float*)d_in[o + 0];
        const float* win  = (const float*)d_in[o + 1];
        const float* cw   = (const float*)d_in[o + 2];
        const float* cb   = (const float*)d_in[o + 3];
        const float* xp   = (const float*)d_in[o + 4];
        const float* dtw  = (const float*)d_in[o + 5];
        const float* dtb  = (const float*)d_in[o + 6];
        const float* Alog = (const float*)d_in[o + 7];
        const float* Dp   = (const float*)d_in[o + 8];
        const float* wout = (const float*)d_in[o + 9];

        for (int b0 = 0; b0 < 8; b0 += nb) {
            const float* xin = input + (size_t)b0 * SEQ * D_MODEL;
            float* cout = out + (size_t)b0 * SEQ * 2 * D_MODEL;

            rmsnorm_k<<<R, 256, 0, stream>>>(xin, nw, xn);
            gemm_f32<0><<<dim3(R / 64, 2 * D_INNER / 64), 256, 0, stream>>>(
                xn, win, xz, nullptr, R, 2 * D_INNER, D_MODEL, 2 * D_INNER, 0, 0);
            conv_silu_k<<<(size_t)R * D_INNER / 256, 256, 0, stream>>>(
                xz, 2 * D_INNER, cw, cb, xcy, dir);
            gemm_f32<0><<<dim3(R / 64, 1), 256, 0, stream>>>(
                xcy, xp, dbl, nullptr, R, 48, D_INNER, 48, 0, 0);
            scan_k<<<nb * 64, 256, 0, stream>>>(
                xcy, dbl, xz, dtw, dtb, Alog, Dp, dir);
            gemm_f32<1><<<dim3(R / 64, D_MODEL / 64), 256, 0, stream>>>(
                xcy, wout, cout, xin, R, D_MODEL, D_INNER, 2 * D_MODEL,
                dir * D_MODEL, D_MODEL);
        }
    }
}

// Round 3
// 2632.829 us; speedup vs baseline: 2.1455x; 2.1455x over previous
//
#include <hip/hip_runtime.h>

#define D_MODEL 256
#define D_INNER 1024
#define NST     16
#define SEQ     2048
#define NC      16          // chunks per sequence
#define TC      128         // steps per chunk (NC*TC == SEQ)
#define LOG2E   1.4426950408889634f

// ---------------- RMSNorm: one block (256 thr) per row -------------------
__global__ __launch_bounds__(256) void rmsnorm_k(const float* __restrict__ x,
                                                 const float* __restrict__ w,
                                                 float* __restrict__ xn) {
    int row = blockIdx.x, t = threadIdx.x;
    float v = x[(size_t)row * D_MODEL + t];
    float s = v * v;
    #pragma unroll
    for (int o = 32; o; o >>= 1) s += __shfl_xor(s, o, 64);
    __shared__ float red[4];
    if ((t & 63) == 0) red[t >> 6] = s;
    __syncthreads();
    float tot = red[0] + red[1] + red[2] + red[3];
    float scale = rsqrtf(tot * (1.0f / D_MODEL) + 1e-5f);
    xn[(size_t)row * D_MODEL + t] = v * scale * w[t];
}

// ---------------- fp32 GEMM: C[M,N] = A[M,K] * W[N,K]^T ------------------
// 64x64 tile, 256 threads, 4x4 per thread. RES=1: += res, write C+coff.
template <int RES>
__global__ __launch_bounds__(256) void gemm_f32(const float* __restrict__ A,
                                                const float* __restrict__ W,
                                                float* __restrict__ C,
                                                const float* __restrict__ res,
                                                int M, int N, int K,
                                                int ldc, int coff, int ldres) {
    __shared__ float As[16][68];
    __shared__ float Ws[16][68];
    const int m0 = blockIdx.x * 64, n0 = blockIdx.y * 64;
    const int t = threadIdx.x;
    const int lr = t >> 2, lk = (t & 3) * 4;
    const int tm = (t & 15) * 4, tn = (t >> 4) * 4;
    float acc[4][4] = {};

    for (int k0 = 0; k0 < K; k0 += 16) {
        float4 av = *(const float4*)(A + (size_t)(m0 + lr) * K + k0 + lk);
        float4 wv = make_float4(0.f, 0.f, 0.f, 0.f);
        if (n0 + lr < N)
            wv = *(const float4*)(W + (size_t)(n0 + lr) * K + k0 + lk);
        As[lk + 0][lr] = av.x; As[lk + 1][lr] = av.y;
        As[lk + 2][lr] = av.z; As[lk + 3][lr] = av.w;
        Ws[lk + 0][lr] = wv.x; Ws[lk + 1][lr] = wv.y;
        Ws[lk + 2][lr] = wv.z; Ws[lk + 3][lr] = wv.w;
        __syncthreads();
        #pragma unroll
        for (int k = 0; k < 16; k++) {
            float a4[4], b4[4];
            *(float4*)a4 = *(const float4*)(&As[k][tm]);
            *(float4*)b4 = *(const float4*)(&Ws[k][tn]);
            #pragma unroll
            for (int i = 0; i < 4; i++)
                #pragma unroll
                for (int j = 0; j < 4; j++)
                    acc[i][j] += a4[i] * b4[j];
        }
        __syncthreads();
    }

    #pragma unroll
    for (int i = 0; i < 4; i++) {
        int mrow = m0 + tm + i;
        #pragma unroll
        for (int j = 0; j < 4; j++) {
            int nc = n0 + tn + j;
            if (nc < N) {
                float v = acc[i][j];
                if (RES) v += res[(size_t)mrow * ldres + nc];
                C[(size_t)mrow * ldc + coff + nc] = v;
            }
        }
    }
}

// ---------------- depthwise causal conv (4 taps) + SiLU ------------------
__global__ __launch_bounds__(256) void conv_silu_k(const float* __restrict__ xi,
                                                   int ldx,
                                                   const float* __restrict__ cw,
                                                   const float* __restrict__ cb,
                                                   float* __restrict__ xc, int dir) {
    int idx = blockIdx.x * 256 + threadIdx.x;   // over R*D_INNER
    int d = idx & (D_INNER - 1);
    int bl = idx >> 10;
    int l = bl & (SEQ - 1);
    float acc = cb[d];
    #pragma unroll
    for (int j = 0; j < 4; j++) {
        int lo = (dir == 0) ? (l - 3 + j) : (l + 3 - j);
        if (lo >= 0 && lo < SEQ)
            acc += cw[d * 4 + j] * xi[(size_t)(bl - l + lo) * ldx + d];
    }
    float s = acc / (1.0f + __expf(-acc));
    xc[(size_t)bl * D_INNER + d] = s;
}

// ------- dt = softplus(dt_low . dt_w + dt_b); g = silu(z) in place -------
__global__ __launch_bounds__(256) void dt_g_k(const float* __restrict__ dbl,
                                              const float* __restrict__ dtw,
                                              const float* __restrict__ dtb,
                                              float* __restrict__ dtout,
                                              float* __restrict__ xz) {
    int idx = blockIdx.x * 256 + threadIdx.x;   // over R*D_INNER
    int d = idx & (D_INNER - 1);
    size_t row = idx >> 10;
    const float* dr = dbl + row * 48;
    float acc = dtb[d];
    #pragma unroll
    for (int j = 0; j < 16; j++) acc += dr[j] * dtw[d * 16 + j];
    float dtv = (acc > 20.0f) ? acc : __logf(1.0f + __expf(acc));
    dtout[idx] = dtv;
    size_t zi = row * (2 * D_INNER) + D_INNER + d;
    float z = xz[zi];
    xz[zi] = z / (1.0f + __expf(-z));            // g = silu(z), in place
}

// ---------------- scan phase 1: per-chunk H (h_in=0) and P ----------------
// thread=(d,n); block = 16 d x 16 n; grid = NC * nb * 64 blocks.
__global__ __launch_bounds__(256) void scan_phase1(const float* __restrict__ xcy,
                                                   const float* __restrict__ dt,
                                                   const float* __restrict__ dbl,
                                                   const float* __restrict__ Alog,
                                                   float* __restrict__ P,
                                                   float* __restrict__ H,
                                                   int nb64, int dir) {
    int t = threadIdx.x;
    int n = t & 15;
    int bx = blockIdx.x;
    int c = bx / nb64; int rem = bx - c * nb64;
    int b = rem >> 6, dg = rem & 63;
    int d = dg * 16 + (t >> 4);

    float A2 = -__expf(Alog[d * NST + n]) * LOG2E;
    float h = 0.0f, S = 0.0f;
    for (int s = 0; s < TC; s++) {
        int q = c * TC + s;
        int l = dir ? (SEQ - 1 - q) : q;
        size_t row = (size_t)b * SEQ + l;
        float dtv = dt[row * D_INNER + d];
        float u   = xcy[row * D_INNER + d];
        float Bn  = dbl[row * 48 + 16 + n];
        float dA  = exp2f(A2 * dtv);
        h = h * dA + (dtv * u) * Bn;
        S += dtv;
    }
    int chain = b * 16384 + dg * 256 + t;
    int NCH = nb64 * 256;
    P[(size_t)c * NCH + chain] = exp2f(A2 * S);
    H[(size_t)c * NCH + chain] = h;
}

// ---------------- scan phase 2: combine chunk states ----------------------
__global__ __launch_bounds__(256) void scan_phase2(const float* __restrict__ P,
                                                   const float* __restrict__ H,
                                                   float* __restrict__ hin,
                                                   int NCH) {
    int chain = blockIdx.x * 256 + threadIdx.x;
    float h = 0.0f;
    #pragma unroll
    for (int c = 0; c < NC; c++) {
        hin[(size_t)c * NCH + chain] = h;
        h = H[(size_t)c * NCH + chain] + P[(size_t)c * NCH + chain] * h;
    }
}

// ---------------- scan phase 3: recurrence + output -----------------------
// y written in place over xcy (u read by the same wave first).
__global__ __launch_bounds__(256) void scan_phase3(float* __restrict__ xcy,
                                                   const float* __restrict__ dt,
                                                   const float* __restrict__ dbl,
                                                   const float* __restrict__ xz,
                                                   const float* __restrict__ Alog,
                                                   const float* __restrict__ Dp,
                                                   const float* __restrict__ hin,
                                                   int nb64, int dir) {
    int t = threadIdx.x;
    int n = t & 15;
    int bx = blockIdx.x;
    int c = bx / nb64; int rem = bx - c * nb64;
    int b = rem >> 6, dg = rem & 63;
    int d = dg * 16 + (t >> 4);

    float A2 = -__expf(Alog[d * NST + n]) * LOG2E;
    float Dd = Dp[d];
    int chain = b * 16384 + dg * 256 + t;
    int NCH = nb64 * 256;
    float h = hin[(size_t)c * NCH + chain];

    for (int s = 0; s < TC; s++) {
        int q = c * TC + s;
        int l = dir ? (SEQ - 1 - q) : q;
        size_t row = (size_t)b * SEQ + l;
        float dtv = dt[row * D_INNER + d];
        float u   = xcy[row * D_INNER + d];
        const float* dr = dbl + row * 48;
        float Bn = dr[16 + n];
        float Cn = dr[32 + n];
        float dA = exp2f(A2 * dtv);
        h = h * dA + (dtv * u) * Bn;

        float p = h * Cn;
        p += __shfl_xor(p, 1, 64);
        p += __shfl_xor(p, 2, 64);
        p += __shfl_xor(p, 4, 64);
        p += __shfl_xor(p, 8, 64);

        if (n == 0) {
            float g = xz[row * (2 * D_INNER) + D_INNER + d];  // silu(z) precomputed
            xcy[row * D_INNER + d] = (p + u * Dd) * g;
        }
    }
}

// ---------------- host launch --------------------------------------------
extern "C" void kernel_launch(void* const* d_in, const int* in_sizes, int n_in,
                              void* d_out, int out_size, void* d_ws, size_t ws_size,
                              hipStream_t stream) {
    const float* input = (const float*)d_in[0];
    float* out = (float*)d_out;

    // per-batch fp32 scratch: xn 256 + xz 2048 + xcy 1024 + dbl 48 + dt 1024
    // per row, plus chunk-state P/H/hin (NC * 16384 * 3 floats per batch)
    const size_t perb = ((size_t)2048 * (256 + 2048 + 1024 + 48 + 1024)
                         + (size_t)NC * 16384 * 3) * 4;
    int nb = 8;
    while (nb > 1 && (size_t)nb * perb > ws_size) nb >>= 1;
    const int R = nb * SEQ;
    const int NCH = nb * 16384;      // chains per batch-chunk

    float* xn  = (float*)d_ws;
    float* xz  = xn  + (size_t)R * D_MODEL;
    float* xcy = xz  + (size_t)R * 2 * D_INNER;
    float* dbl = xcy + (size_t)R * D_INNER;
    float* dt  = dbl + (size_t)R * 48;
    float* Pb  = dt  + (size_t)R * D_INNER;
    float* Hb  = Pb  + (size_t)NC * NCH;
    float* hin = Hb  + (size_t)NC * NCH;

    for (int dir = 0; dir < 2; dir++) {
        int o = 1 + dir * 10;
        const float* nw   = (const float*)d_in[o + 0];
        const float* win  = (const float*)d_in[o + 1];
        const float* cw   = (const float*)d_in[o + 2];
        const float* cb   = (const float*)d_in[o + 3];
        const float* xp   = (const float*)d_in[o + 4];
        const float* dtw  = (const float*)d_in[o + 5];
        const float* dtb  = (const float*)d_in[o + 6];
        const float* Alog = (const float*)d_in[o + 7];
        const float* Dp   = (const float*)d_in[o + 8];
        const float* wout = (const float*)d_in[o + 9];

        for (int b0 = 0; b0 < 8; b0 += nb) {
            const float* xin = input + (size_t)b0 * SEQ * D_MODEL;
            float* cout = out + (size_t)b0 * SEQ * 2 * D_MODEL;

            rmsnorm_k<<<R, 256, 0, stream>>>(xin, nw, xn);
            gemm_f32<0><<<dim3(R / 64, 2 * D_INNER / 64), 256, 0, stream>>>(
                xn, win, xz, nullptr, R, 2 * D_INNER, D_MODEL, 2 * D_INNER, 0, 0);
            conv_silu_k<<<(size_t)R * D_INNER / 256, 256, 0, stream>>>(
                xz, 2 * D_INNER, cw, cb, xcy, dir);
            gemm_f32<0><<<dim3(R / 64, 1), 256, 0, stream>>>(
                xcy, xp, dbl, nullptr, R, 48, D_INNER, 48, 0, 0);
            dt_g_k<<<(size_t)R * D_INNER / 256, 256, 0, stream>>>(
                dbl, dtw, dtb, dt, xz);
            scan_phase1<<<NC * nb * 64, 256, 0, stream>>>(
                xcy, dt, dbl, Alog, Pb, Hb, nb * 64, dir);
            scan_phase2<<<NCH / 256, 256, 0, stream>>>(Pb, Hb, hin, NCH);
            scan_phase3<<<NC * nb * 64, 256, 0, stream>>>(
                xcy, dt, dbl, xz, Alog, Dp, hin, nb * 64, dir);
            gemm_f32<1><<<dim3(R / 64, D_MODEL / 64), 256, 0, stream>>>(
                xcy, wout, cout, xin, R, D_MODEL, D_INNER, 2 * D_MODEL,
                dir * D_MODEL, D_MODEL);
        }
    }
}

// Round 4
// 2200.460 us; speedup vs baseline: 2.5670x; 1.1965x over previous
//
#include <hip/hip_runtime.h>

#define D_MODEL 256
#define D_INNER 1024
#define NST     16
#define SEQ     2048
#define LOG2E   1.4426950408889634f

// ---------------- RMSNorm: one block (256 thr) per row -------------------
__global__ __launch_bounds__(256) void rmsnorm_k(const float* __restrict__ x,
                                                 const float* __restrict__ w,
                                                 float* __restrict__ xn) {
    int row = blockIdx.x, t = threadIdx.x;
    float v = x[(size_t)row * D_MODEL + t];
    float s = v * v;
    #pragma unroll
    for (int o = 32; o; o >>= 1) s += __shfl_xor(s, o, 64);
    __shared__ float red[4];
    if ((t & 63) == 0) red[t >> 6] = s;
    __syncthreads();
    float tot = red[0] + red[1] + red[2] + red[3];
    float scale = rsqrtf(tot * (1.0f / D_MODEL) + 1e-5f);
    xn[(size_t)row * D_MODEL + t] = v * scale * w[t];
}

// ------- fp32 GEMM 128x128 tile, 8x8/thread: C = A[M,K] * W[N,K]^T -------
// M,N,K all multiples of 128/128/16 at call sites (no guards).
// RES=1: C[m*ldc+coff+n] = acc + res[m*ldres+n]
template <int RES>
__global__ __launch_bounds__(256) void gemm128(const float* __restrict__ A,
                                               const float* __restrict__ W,
                                               float* __restrict__ C,
                                               const float* __restrict__ res,
                                               int K, int ldc, int coff, int ldres) {
    __shared__ float As[16][132];
    __shared__ float Ws[16][132];
    const int m0 = blockIdx.x * 128, n0 = blockIdx.y * 128;
    const int t = threadIdx.x;
    const int sr = t >> 1, sk = (t & 1) * 8;     // staging: row, k-offset
    const int jm = (t & 15) * 4;                 // compute: m float4 base
    const int jn = (t >> 4) * 4;                 // compute: n float4 base

    float acc[2][2][4][4] = {};                  // [mi][ni][i][j]

    for (int k0 = 0; k0 < K; k0 += 16) {
        float4 a0 = *(const float4*)(A + (size_t)(m0 + sr) * K + k0 + sk);
        float4 a1 = *(const float4*)(A + (size_t)(m0 + sr) * K + k0 + sk + 4);
        float4 w0 = *(const float4*)(W + (size_t)(n0 + sr) * K + k0 + sk);
        float4 w1 = *(const float4*)(W + (size_t)(n0 + sr) * K + k0 + sk + 4);
        As[sk + 0][sr] = a0.x; As[sk + 1][sr] = a0.y;
        As[sk + 2][sr] = a0.z; As[sk + 3][sr] = a0.w;
        As[sk + 4][sr] = a1.x; As[sk + 5][sr] = a1.y;
        As[sk + 6][sr] = a1.z; As[sk + 7][sr] = a1.w;
        Ws[sk + 0][sr] = w0.x; Ws[sk + 1][sr] = w0.y;
        Ws[sk + 2][sr] = w0.z; Ws[sk + 3][sr] = w0.w;
        Ws[sk + 4][sr] = w1.x; Ws[sk + 5][sr] = w1.y;
        Ws[sk + 6][sr] = w1.z; Ws[sk + 7][sr] = w1.w;
        __syncthreads();
        #pragma unroll 4
        for (int k = 0; k < 16; k++) {
            float a[2][4], b[2][4];
            *(float4*)a[0] = *(const float4*)(&As[k][jm]);
            *(float4*)a[1] = *(const float4*)(&As[k][jm + 64]);
            *(float4*)b[0] = *(const float4*)(&Ws[k][jn]);
            *(float4*)b[1] = *(const float4*)(&Ws[k][jn + 64]);
            #pragma unroll
            for (int mi = 0; mi < 2; mi++)
                #pragma unroll
                for (int ni = 0; ni < 2; ni++)
                    #pragma unroll
                    for (int i = 0; i < 4; i++)
                        #pragma unroll
                        for (int j = 0; j < 4; j++)
                            acc[mi][ni][i][j] += a[mi][i] * b[ni][j];
        }
        __syncthreads();
    }

    #pragma unroll
    for (int mi = 0; mi < 2; mi++)
        #pragma unroll
        for (int i = 0; i < 4; i++) {
            int mrow = m0 + mi * 64 + jm + i;
            #pragma unroll
            for (int ni = 0; ni < 2; ni++) {
                int nc = n0 + ni * 64 + jn;
                float4 v = *(float4*)acc[mi][ni][i];  // wrong orientation? no:
                // acc[mi][ni][i][j] over j is the float4 along n.
                if (RES) {
                    const float4 rv = *(const float4*)(res + (size_t)mrow * ldres + nc);
                    v.x += rv.x; v.y += rv.y; v.z += rv.z; v.w += rv.w;
                }
                *(float4*)(C + (size_t)mrow * ldc + coff + nc) = v;
            }
        }
}

// ------- x_proj GEMM, split-K with atomic accumulate: N=48, K slice ------
__global__ __launch_bounds__(256) void gemm_xproj(const float* __restrict__ A,
                                                  const float* __restrict__ W,
                                                  float* __restrict__ C,
                                                  int Kfull, int Kslice) {
    __shared__ float As[16][68];
    __shared__ float Ws[16][68];
    const int m0 = blockIdx.x * 64;
    const int kbase = blockIdx.y * Kslice;
    const int t = threadIdx.x;
    const int lr = t >> 2, lk = (t & 3) * 4;
    const int tm = (t & 15) * 4, tn = (t >> 4) * 4;
    float acc[4][4] = {};

    for (int k0 = kbase; k0 < kbase + Kslice; k0 += 16) {
        float4 av = *(const float4*)(A + (size_t)(m0 + lr) * Kfull + k0 + lk);
        float4 wv = make_float4(0.f, 0.f, 0.f, 0.f);
        if (lr < 48)
            wv = *(const float4*)(W + (size_t)lr * Kfull + k0 + lk);
        As[lk + 0][lr] = av.x; As[lk + 1][lr] = av.y;
        As[lk + 2][lr] = av.z; As[lk + 3][lr] = av.w;
        Ws[lk + 0][lr] = wv.x; Ws[lk + 1][lr] = wv.y;
        Ws[lk + 2][lr] = wv.z; Ws[lk + 3][lr] = wv.w;
        __syncthreads();
        #pragma unroll
        for (int k = 0; k < 16; k++) {
            float a4[4], b4[4];
            *(float4*)a4 = *(const float4*)(&As[k][tm]);
            *(float4*)b4 = *(const float4*)(&Ws[k][tn]);
            #pragma unroll
            for (int i = 0; i < 4; i++)
                #pragma unroll
                for (int j = 0; j < 4; j++)
                    acc[i][j] += a4[i] * b4[j];
        }
        __syncthreads();
    }

    #pragma unroll
    for (int i = 0; i < 4; i++) {
        int mrow = m0 + tm + i;
        #pragma unroll
        for (int j = 0; j < 4; j++) {
            int nc = tn + j;
            if (nc < 48)
                atomicAdd(&C[(size_t)mrow * 48 + nc], acc[i][j]);
        }
    }
}

// ---------------- depthwise causal conv (4 taps) + SiLU ------------------
__global__ __launch_bounds__(256) void conv_silu_k(const float* __restrict__ xi,
                                                   const float* __restrict__ cw,
                                                   const float* __restrict__ cb,
                                                   float* __restrict__ xc, int dir) {
    int idx = blockIdx.x * 256 + threadIdx.x;   // over R*D_INNER
    int d = idx & (D_INNER - 1);
    int bl = idx >> 10;
    int l = bl & (SEQ - 1);
    float acc = cb[d];
    #pragma unroll
    for (int j = 0; j < 4; j++) {
        int lo = (dir == 0) ? (l - 3 + j) : (l + 3 - j);
        if (lo >= 0 && lo < SEQ)
            acc += cw[d * 4 + j] * xi[(size_t)(bl - l + lo) * (2 * D_INNER) + d];
    }
    float s = acc / (1.0f + __expf(-acc));
    xc[(size_t)bl * D_INNER + d] = s;
}

// ------- dt = softplus(dt_low . dt_w + dt_b); g = silu(z) in place -------
__global__ __launch_bounds__(256) void dt_g_k(const float* __restrict__ dbl,
                                              const float* __restrict__ dtw,
                                              const float* __restrict__ dtb,
                                              float* __restrict__ dtout,
                                              float* __restrict__ xz) {
    int idx = blockIdx.x * 256 + threadIdx.x;   // over R*D_INNER
    int d = idx & (D_INNER - 1);
    size_t row = idx >> 10;
    const float* dr = dbl + row * 48;
    float acc = dtb[d];
    #pragma unroll
    for (int j = 0; j < 16; j++) acc += dr[j] * dtw[d * 16 + j];
    float dtv = (acc > 20.0f) ? acc : __logf(1.0f + __expf(acc));
    dtout[idx] = dtv;
    size_t zi = row * (2 * D_INNER) + D_INNER + d;
    float z = xz[zi];
    xz[zi] = z / (1.0f + __expf(-z));            // g = silu(z), in place
}

// ---------------- scan phase 1: per-chunk H (h_in=0) and P ----------------
// thread = one d-chain; h[16], A2[16] in registers; B wave-uniform loads.
__global__ __launch_bounds__(256) void scan_p1(const float* __restrict__ xcy,
                                               const float* __restrict__ dtb_,
                                               const float* __restrict__ dbl,
                                               const float* __restrict__ Alog,
                                               float* __restrict__ P,
                                               float* __restrict__ H,
                                               int nb, int TC, int dir) {
    int t = threadIdx.x;
    int nblk4 = nb * 4;
    int c = blockIdx.x / nblk4;
    int rem = blockIdx.x - c * nblk4;
    int b = rem >> 2, dblk = rem & 3;
    int d = dblk * 256 + t;

    float A2[16];
    const float* ap = Alog + (size_t)d * NST;
    #pragma unroll
    for (int n = 0; n < 16; n++) A2[n] = -__expf(ap[n]) * LOG2E;
    float h[16] = {0,0,0,0,0,0,0,0,0,0,0,0,0,0,0,0};
    float S = 0.0f;

    for (int s = 0; s < TC; s++) {
        int q = c * TC + s;
        int l = dir ? (SEQ - 1 - q) : q;
        size_t row = (size_t)b * SEQ + l;
        float dt = dtb_[row * D_INNER + d];
        float u  = xcy[row * D_INNER + d];
        const float* dr = dbl + row * 48 + 16;
        float B[16];
        *(float4*)&B[0]  = *(const float4*)(dr);
        *(float4*)&B[4]  = *(const float4*)(dr + 4);
        *(float4*)&B[8]  = *(const float4*)(dr + 8);
        *(float4*)&B[12] = *(const float4*)(dr + 12);
        float dtu = dt * u;
        S += dt;
        #pragma unroll
        for (int n = 0; n < 16; n++)
            h[n] = h[n] * exp2f(A2[n] * dt) + dtu * B[n];
    }

    size_t NCH = (size_t)nb * 16384;
    size_t base = (size_t)c * NCH + ((size_t)b * 1024 + d) * 16;
    float Pv[16];
    #pragma unroll
    for (int n = 0; n < 16; n++) Pv[n] = exp2f(A2[n] * S);
    #pragma unroll
    for (int n = 0; n < 16; n += 4) {
        *(float4*)&H[base + n] = *(float4*)&h[n];
        *(float4*)&P[base + n] = *(float4*)&Pv[n];
    }
}

// ------- scan phase 2: combine chunk states; H repurposed as h_in --------
__global__ __launch_bounds__(256) void scan_p2(const float* __restrict__ P,
                                               float* __restrict__ H,
                                               int NCH, int NC) {
    size_t chain = (size_t)blockIdx.x * 256 + threadIdx.x;
    float h = 0.0f;
    for (int c = 0; c < NC; c++) {
        size_t i = (size_t)c * NCH + chain;
        float Hc = H[i], Pc = P[i];
        H[i] = h;                 // h_in for chunk c
        h = Hc + Pc * h;
    }
}

// ---------------- scan phase 3: recurrence + output -----------------------
__global__ __launch_bounds__(256) void scan_p3(float* __restrict__ xcy,
                                               const float* __restrict__ dtb_,
                                               const float* __restrict__ dbl,
                                               const float* __restrict__ xz,
                                               const float* __restrict__ Alog,
                                               const float* __restrict__ Dp,
                                               const float* __restrict__ hin,
                                               int nb, int TC, int dir) {
    int t = threadIdx.x;
    int nblk4 = nb * 4;
    int c = blockIdx.x / nblk4;
    int rem = blockIdx.x - c * nblk4;
    int b = rem >> 2, dblk = rem & 3;
    int d = dblk * 256 + t;

    float A2[16];
    const float* ap = Alog + (size_t)d * NST;
    #pragma unroll
    for (int n = 0; n < 16; n++) A2[n] = -__expf(ap[n]) * LOG2E;
    float Dd = Dp[d];

    size_t NCH = (size_t)nb * 16384;
    size_t base = (size_t)c * NCH + ((size_t)b * 1024 + d) * 16;
    float h[16];
    #pragma unroll
    for (int n = 0; n < 16; n += 4)
        *(float4*)&h[n] = *(const float4*)&hin[base + n];

    for (int s = 0; s < TC; s++) {
        int q = c * TC + s;
        int l = dir ? (SEQ - 1 - q) : q;
        size_t row = (size_t)b * SEQ + l;
        float dt = dtb_[row * D_INNER + d];
        float u  = xcy[row * D_INNER + d];
        const float* dr = dbl + row * 48;
        float B[16], Cv[16];
        *(float4*)&B[0]   = *(const float4*)(dr + 16);
        *(float4*)&B[4]   = *(const float4*)(dr + 20);
        *(float4*)&B[8]   = *(const float4*)(dr + 24);
        *(float4*)&B[12]  = *(const float4*)(dr + 28);
        *(float4*)&Cv[0]  = *(const float4*)(dr + 32);
        *(float4*)&Cv[4]  = *(const float4*)(dr + 36);
        *(float4*)&Cv[8]  = *(const float4*)(dr + 40);
        *(float4*)&Cv[12] = *(const float4*)(dr + 44);
        float dtu = dt * u;
        #pragma unroll
        for (int n = 0; n < 16; n++)
            h[n] = h[n] * exp2f(A2[n] * dt) + dtu * B[n];

        float p0 = h[0]*Cv[0] + h[1]*Cv[1] + h[2]*Cv[2] + h[3]*Cv[3];
        float p1 = h[4]*Cv[4] + h[5]*Cv[5] + h[6]*Cv[6] + h[7]*Cv[7];
        float p2 = h[8]*Cv[8] + h[9]*Cv[9] + h[10]*Cv[10] + h[11]*Cv[11];
        float p3 = h[12]*Cv[12] + h[13]*Cv[13] + h[14]*Cv[14] + h[15]*Cv[15];
        float y = (p0 + p1) + (p2 + p3);

        float g = xz[row * (2 * D_INNER) + D_INNER + d];
        xcy[row * D_INNER + d] = (y + u * Dd) * g;
    }
}

// ---------------- host launch --------------------------------------------
extern "C" void kernel_launch(void* const* d_in, const int* in_sizes, int n_in,
                              void* d_out, int out_size, void* d_ws, size_t ws_size,
                              hipStream_t stream) {
    const float* input = (const float*)d_in[0];
    float* out = (float*)d_out;

    // P/H: fixed 256*16384 floats each (NC*nb*16384 with NC = 256/nb).
    const size_t phfix = (size_t)2 * 256 * 16384 * 4;         // 33.6 MB
    const size_t perb = (size_t)2048 * (256 + 2048 + 1024 + 48 + 1024) * 4;  // 36.0 MB
    int nb = 8;
    while (nb > 1 && phfix + (size_t)nb * perb > ws_size) nb >>= 1;
    const int NC = 256 / nb;
    const int TC = SEQ / NC;
    const int R = nb * SEQ;
    const int NCH = nb * 16384;

    float* P   = (float*)d_ws;
    float* H   = P + (size_t)256 * 16384;
    float* xn  = H + (size_t)256 * 16384;
    float* xz  = xn  + (size_t)R * D_MODEL;
    float* xcy = xz  + (size_t)R * 2 * D_INNER;
    float* dbl = xcy + (size_t)R * D_INNER;
    float* dt  = dbl + (size_t)R * 48;

    for (int dir = 0; dir < 2; dir++) {
        int o = 1 + dir * 10;
        const float* nw   = (const float*)d_in[o + 0];
        const float* win  = (const float*)d_in[o + 1];
        const float* cw   = (const float*)d_in[o + 2];
        const float* cb   = (const float*)d_in[o + 3];
        const float* xp   = (const float*)d_in[o + 4];
        const float* dtw  = (const float*)d_in[o + 5];
        const float* dtbv = (const float*)d_in[o + 6];
        const float* Alog = (const float*)d_in[o + 7];
        const float* Dp   = (const float*)d_in[o + 8];
        const float* wout = (const float*)d_in[o + 9];

        for (int b0 = 0; b0 < 8; b0 += nb) {
            const float* xin = input + (size_t)b0 * SEQ * D_MODEL;
            float* cout = out + (size_t)b0 * SEQ * 2 * D_MODEL;

            rmsnorm_k<<<R, 256, 0, stream>>>(xin, nw, xn);
            gemm128<0><<<dim3(R / 128, 2 * D_INNER / 128), 256, 0, stream>>>(
                xn, win, xz, nullptr, D_MODEL, 2 * D_INNER, 0, 0);
            conv_silu_k<<<(size_t)R * D_INNER / 256, 256, 0, stream>>>(
                xz, cw, cb, xcy, dir);
            hipMemsetAsync(dbl, 0, (size_t)R * 48 * 4, stream);
            gemm_xproj<<<dim3(R / 64, 4), 256, 0, stream>>>(
                xcy, xp, dbl, D_INNER, D_INNER / 4);
            dt_g_k<<<(size_t)R * D_INNER / 256, 256, 0, stream>>>(
                dbl, dtw, dtbv, dt, xz);
            scan_p1<<<NC * nb * 4, 256, 0, stream>>>(
                xcy, dt, dbl, Alog, P, H, nb, TC, dir);
            scan_p2<<<NCH / 256, 256, 0, stream>>>(P, H, NCH, NC);
            scan_p3<<<NC * nb * 4, 256, 0, stream>>>(
                xcy, dt, dbl, xz, Alog, Dp, H, nb, TC, dir);
            gemm128<1><<<dim3(R / 128, D_MODEL / 128), 256, 0, stream>>>(
                xcy, wout, cout, xin, D_INNER, 2 * D_MODEL, dir * D_MODEL, D_MODEL);
        }
    }
}

// Round 5
// 1814.058 us; speedup vs baseline: 3.1138x; 1.2130x over previous
//
#include <hip/hip_runtime.h>

#define D_MODEL 256
#define D_INNER 1024
#define NST     16
#define SEQ     2048
#define LOG2E   1.4426950408889634f

// ---------------- RMSNorm: one block (256 thr) per row -------------------
__global__ __launch_bounds__(256) void rmsnorm_k(const float* __restrict__ x,
                                                 const float* __restrict__ w,
                                                 float* __restrict__ xn) {
    int row = blockIdx.x, t = threadIdx.x;
    float v = x[(size_t)row * D_MODEL + t];
    float s = v * v;
    #pragma unroll
    for (int o = 32; o; o >>= 1) s += __shfl_xor(s, o, 64);
    __shared__ float red[4];
    if ((t & 63) == 0) red[t >> 6] = s;
    __syncthreads();
    float tot = red[0] + red[1] + red[2] + red[3];
    float scale = rsqrtf(tot * (1.0f / D_MODEL) + 1e-5f);
    xn[(size_t)row * D_MODEL + t] = v * scale * w[t];
}

// ------- fp32 GEMM 128x128 tile, 8x8/thread: C = A[M,K] * W[N,K]^T -------
__global__ __launch_bounds__(256) void gemm128(const float* __restrict__ A,
                                               const float* __restrict__ W,
                                               float* __restrict__ C,
                                               int K, int ldc) {
    __shared__ float As[16][132];
    __shared__ float Ws[16][132];
    const int m0 = blockIdx.x * 128, n0 = blockIdx.y * 128;
    const int t = threadIdx.x;
    const int sr = t >> 1, sk = (t & 1) * 8;
    const int jm = (t & 15) * 4;
    const int jn = (t >> 4) * 4;

    float acc[2][2][4][4] = {};

    for (int k0 = 0; k0 < K; k0 += 16) {
        float4 a0 = *(const float4*)(A + (size_t)(m0 + sr) * K + k0 + sk);
        float4 a1 = *(const float4*)(A + (size_t)(m0 + sr) * K + k0 + sk + 4);
        float4 w0 = *(const float4*)(W + (size_t)(n0 + sr) * K + k0 + sk);
        float4 w1 = *(const float4*)(W + (size_t)(n0 + sr) * K + k0 + sk + 4);
        As[sk + 0][sr] = a0.x; As[sk + 1][sr] = a0.y;
        As[sk + 2][sr] = a0.z; As[sk + 3][sr] = a0.w;
        As[sk + 4][sr] = a1.x; As[sk + 5][sr] = a1.y;
        As[sk + 6][sr] = a1.z; As[sk + 7][sr] = a1.w;
        Ws[sk + 0][sr] = w0.x; Ws[sk + 1][sr] = w0.y;
        Ws[sk + 2][sr] = w0.z; Ws[sk + 3][sr] = w0.w;
        Ws[sk + 4][sr] = w1.x; Ws[sk + 5][sr] = w1.y;
        Ws[sk + 6][sr] = w1.z; Ws[sk + 7][sr] = w1.w;
        __syncthreads();
        #pragma unroll 4
        for (int k = 0; k < 16; k++) {
            float a[2][4], b[2][4];
            *(float4*)a[0] = *(const float4*)(&As[k][jm]);
            *(float4*)a[1] = *(const float4*)(&As[k][jm + 64]);
            *(float4*)b[0] = *(const float4*)(&Ws[k][jn]);
            *(float4*)b[1] = *(const float4*)(&Ws[k][jn + 64]);
            #pragma unroll
            for (int mi = 0; mi < 2; mi++)
                #pragma unroll
                for (int ni = 0; ni < 2; ni++)
                    #pragma unroll
                    for (int i = 0; i < 4; i++)
                        #pragma unroll
                        for (int j = 0; j < 4; j++)
                            acc[mi][ni][i][j] += a[mi][i] * b[ni][j];
        }
        __syncthreads();
    }

    #pragma unroll
    for (int mi = 0; mi < 2; mi++)
        #pragma unroll
        for (int i = 0; i < 4; i++) {
            int mrow = m0 + mi * 64 + jm + i;
            #pragma unroll
            for (int ni = 0; ni < 2; ni++) {
                int nc = n0 + ni * 64 + jn;
                *(float4*)(C + (size_t)mrow * ldc + nc) = *(float4*)acc[mi][ni][i];
            }
        }
}

// ------ out_proj split-K: partial[z] = A[M,1024] * W[256,1024]^T slice ----
// grid (M/128, 2, 4); K-slice 256; partials: pbuf[z*M*256 + m*256 + n]
__global__ __launch_bounds__(256) void gemm_osk(const float* __restrict__ A,
                                                const float* __restrict__ W,
                                                float* __restrict__ pbuf,
                                                int M) {
    __shared__ float As[16][132];
    __shared__ float Ws[16][132];
    const int m0 = blockIdx.x * 128, n0 = blockIdx.y * 128;
    const int kbase = blockIdx.z * 256;
    const int t = threadIdx.x;
    const int sr = t >> 1, sk = (t & 1) * 8;
    const int jm = (t & 15) * 4;
    const int jn = (t >> 4) * 4;

    float acc[2][2][4][4] = {};

    for (int k0 = kbase; k0 < kbase + 256; k0 += 16) {
        float4 a0 = *(const float4*)(A + (size_t)(m0 + sr) * D_INNER + k0 + sk);
        float4 a1 = *(const float4*)(A + (size_t)(m0 + sr) * D_INNER + k0 + sk + 4);
        float4 w0 = *(const float4*)(W + (size_t)(n0 + sr) * D_INNER + k0 + sk);
        float4 w1 = *(const float4*)(W + (size_t)(n0 + sr) * D_INNER + k0 + sk + 4);
        As[sk + 0][sr] = a0.x; As[sk + 1][sr] = a0.y;
        As[sk + 2][sr] = a0.z; As[sk + 3][sr] = a0.w;
        As[sk + 4][sr] = a1.x; As[sk + 5][sr] = a1.y;
        As[sk + 6][sr] = a1.z; As[sk + 7][sr] = a1.w;
        Ws[sk + 0][sr] = w0.x; Ws[sk + 1][sr] = w0.y;
        Ws[sk + 2][sr] = w0.z; Ws[sk + 3][sr] = w0.w;
        Ws[sk + 4][sr] = w1.x; Ws[sk + 5][sr] = w1.y;
        Ws[sk + 6][sr] = w1.z; Ws[sk + 7][sr] = w1.w;
        __syncthreads();
        #pragma unroll 4
        for (int k = 0; k < 16; k++) {
            float a[2][4], b[2][4];
            *(float4*)a[0] = *(const float4*)(&As[k][jm]);
            *(float4*)a[1] = *(const float4*)(&As[k][jm + 64]);
            *(float4*)b[0] = *(const float4*)(&Ws[k][jn]);
            *(float4*)b[1] = *(const float4*)(&Ws[k][jn + 64]);
            #pragma unroll
            for (int mi = 0; mi < 2; mi++)
                #pragma unroll
                for (int ni = 0; ni < 2; ni++)
                    #pragma unroll
                    for (int i = 0; i < 4; i++)
                        #pragma unroll
                        for (int j = 0; j < 4; j++)
                            acc[mi][ni][i][j] += a[mi][i] * b[ni][j];
        }
        __syncthreads();
    }

    float* pb = pbuf + (size_t)blockIdx.z * M * 256;
    #pragma unroll
    for (int mi = 0; mi < 2; mi++)
        #pragma unroll
        for (int i = 0; i < 4; i++) {
            int mrow = m0 + mi * 64 + jm + i;
            #pragma unroll
            for (int ni = 0; ni < 2; ni++) {
                int nc = n0 + ni * 64 + jn;
                *(float4*)(pb + (size_t)mrow * 256 + nc) = *(float4*)acc[mi][ni][i];
            }
        }
}

// ------ reduce 4 partials + residual -> out[m, coff + n] ------------------
__global__ __launch_bounds__(256) void reduce_out_k(const float* __restrict__ pbuf,
                                                    const float* __restrict__ res,
                                                    float* __restrict__ out,
                                                    int M, int coff) {
    int idx = blockIdx.x * 256 + threadIdx.x;     // over M*64 float4 groups
    int m = idx >> 6, n4 = (idx & 63) * 4;
    size_t e = (size_t)m * 256 + n4;
    size_t stride = (size_t)M * 256;
    float4 v = *(const float4*)(res + e);
    #pragma unroll
    for (int s = 0; s < 4; s++) {
        float4 p = *(const float4*)(pbuf + s * stride + e);
        v.x += p.x; v.y += p.y; v.z += p.z; v.w += p.w;
    }
    *(float4*)(out + (size_t)m * 512 + coff + n4) = v;
}

// ------- x_proj GEMM, split-K with atomic accumulate: N=48 ---------------
__global__ __launch_bounds__(256) void gemm_xproj(const float* __restrict__ A,
                                                  const float* __restrict__ W,
                                                  float* __restrict__ C,
                                                  int Kfull, int Kslice) {
    __shared__ float As[16][68];
    __shared__ float Ws[16][68];
    const int m0 = blockIdx.x * 64;
    const int kbase = blockIdx.y * Kslice;
    const int t = threadIdx.x;
    const int lr = t >> 2, lk = (t & 3) * 4;
    const int tm = (t & 15) * 4, tn = (t >> 4) * 4;
    float acc[4][4] = {};

    for (int k0 = kbase; k0 < kbase + Kslice; k0 += 16) {
        float4 av = *(const float4*)(A + (size_t)(m0 + lr) * Kfull + k0 + lk);
        float4 wv = make_float4(0.f, 0.f, 0.f, 0.f);
        if (lr < 48)
            wv = *(const float4*)(W + (size_t)lr * Kfull + k0 + lk);
        As[lk + 0][lr] = av.x; As[lk + 1][lr] = av.y;
        As[lk + 2][lr] = av.z; As[lk + 3][lr] = av.w;
        Ws[lk + 0][lr] = wv.x; Ws[lk + 1][lr] = wv.y;
        Ws[lk + 2][lr] = wv.z; Ws[lk + 3][lr] = wv.w;
        __syncthreads();
        #pragma unroll
        for (int k = 0; k < 16; k++) {
            float a4[4], b4[4];
            *(float4*)a4 = *(const float4*)(&As[k][tm]);
            *(float4*)b4 = *(const float4*)(&Ws[k][tn]);
            #pragma unroll
            for (int i = 0; i < 4; i++)
                #pragma unroll
                for (int j = 0; j < 4; j++)
                    acc[i][j] += a4[i] * b4[j];
        }
        __syncthreads();
    }

    #pragma unroll
    for (int i = 0; i < 4; i++) {
        int mrow = m0 + tm + i;
        #pragma unroll
        for (int j = 0; j < 4; j++) {
            int nc = tn + j;
            if (nc < 48)
                atomicAdd(&C[(size_t)mrow * 48 + nc], acc[i][j]);
        }
    }
}

// ---------------- depthwise causal conv (4 taps) + SiLU ------------------
__global__ __launch_bounds__(256) void conv_silu_k(const float* __restrict__ xi,
                                                   const float* __restrict__ cw,
                                                   const float* __restrict__ cb,
                                                   float* __restrict__ xc, int dir) {
    int idx = blockIdx.x * 256 + threadIdx.x;
    int d = idx & (D_INNER - 1);
    int bl = idx >> 10;
    int l = bl & (SEQ - 1);
    float acc = cb[d];
    #pragma unroll
    for (int j = 0; j < 4; j++) {
        int lo = (dir == 0) ? (l - 3 + j) : (l + 3 - j);
        if (lo >= 0 && lo < SEQ)
            acc += cw[d * 4 + j] * xi[(size_t)(bl - l + lo) * (2 * D_INNER) + d];
    }
    float s = acc / (1.0f + __expf(-acc));
    xc[(size_t)bl * D_INNER + d] = s;
}

// ------- dt = softplus(dt_low . dt_w + dt_b); g = silu(z) in place -------
__global__ __launch_bounds__(256) void dt_g_k(const float* __restrict__ dbl,
                                              const float* __restrict__ dtw,
                                              const float* __restrict__ dtb,
                                              float* __restrict__ dtout,
                                              float* __restrict__ xz) {
    int idx = blockIdx.x * 256 + threadIdx.x;
    int d = idx & (D_INNER - 1);
    size_t row = idx >> 10;
    const float* dr = dbl + row * 48;
    float acc = dtb[d];
    #pragma unroll
    for (int j = 0; j < 16; j++) acc += dr[j] * dtw[d * 16 + j];
    float dtv = (acc > 20.0f) ? acc : __logf(1.0f + __expf(acc));
    dtout[idx] = dtv;
    size_t zi = row * (2 * D_INNER) + D_INNER + d;
    float z = xz[zi];
    xz[zi] = z / (1.0f + __expf(-z));
}

// ---------------- scan phase 1: per-chunk H (h_in=0) and P ----------------
__global__ __launch_bounds__(256) void scan_p1(const float* __restrict__ xcy,
                                               const float* __restrict__ dtb_,
                                               const float* __restrict__ dbl,
                                               const float* __restrict__ Alog,
                                               float* __restrict__ P,
                                               float* __restrict__ H,
                                               int nb, int TC, int dir) {
    int t = threadIdx.x;
    int nblk4 = nb * 4;
    int c = blockIdx.x / nblk4;
    int rem = blockIdx.x - c * nblk4;
    int b = rem >> 2, dblk = rem & 3;
    int d = dblk * 256 + t;

    float A2[16];
    const float* ap = Alog + (size_t)d * NST;
    #pragma unroll
    for (int n = 0; n < 16; n++) A2[n] = -__expf(ap[n]) * LOG2E;
    float h[16] = {0,0,0,0,0,0,0,0,0,0,0,0,0,0,0,0};
    float S = 0.0f;

    for (int s = 0; s < TC; s++) {
        int q = c * TC + s;
        int l = dir ? (SEQ - 1 - q) : q;
        size_t row = (size_t)b * SEQ + l;
        float dt = dtb_[row * D_INNER + d];
        float u  = xcy[row * D_INNER + d];
        const float* dr = dbl + row * 48 + 16;
        float B[16];
        *(float4*)&B[0]  = *(const float4*)(dr);
        *(float4*)&B[4]  = *(const float4*)(dr + 4);
        *(float4*)&B[8]  = *(const float4*)(dr + 8);
        *(float4*)&B[12] = *(const float4*)(dr + 12);
        float dtu = dt * u;
        S += dt;
        #pragma unroll
        for (int n = 0; n < 16; n++)
            h[n] = h[n] * exp2f(A2[n] * dt) + dtu * B[n];
    }

    size_t NCH = (size_t)nb * 16384;
    size_t base = (size_t)c * NCH + ((size_t)b * 1024 + d) * 16;
    float Pv[16];
    #pragma unroll
    for (int n = 0; n < 16; n++) Pv[n] = exp2f(A2[n] * S);
    #pragma unroll
    for (int n = 0; n < 16; n += 4) {
        *(float4*)&H[base + n] = *(float4*)&h[n];
        *(float4*)&P[base + n] = *(float4*)&Pv[n];
    }
}

// ------- scan phase 2: combine chunk states; H repurposed as h_in --------
__global__ __launch_bounds__(256) void scan_p2(const float* __restrict__ P,
                                               float* __restrict__ H,
                                               int NCH, int NC) {
    size_t chain = (size_t)blockIdx.x * 256 + threadIdx.x;
    float h = 0.0f;
    for (int c = 0; c < NC; c++) {
        size_t i = (size_t)c * NCH + chain;
        float Hc = H[i], Pc = P[i];
        H[i] = h;
        h = Hc + Pc * h;
    }
}

// ---------------- scan phase 3: recurrence + output -----------------------
__global__ __launch_bounds__(256) void scan_p3(float* __restrict__ xcy,
                                               const float* __restrict__ dtb_,
                                               const float* __restrict__ dbl,
                                               const float* __restrict__ xz,
                                               const float* __restrict__ Alog,
                                               const float* __restrict__ Dp,
                                               const float* __restrict__ hin,
                                               int nb, int TC, int dir) {
    int t = threadIdx.x;
    int nblk4 = nb * 4;
    int c = blockIdx.x / nblk4;
    int rem = blockIdx.x - c * nblk4;
    int b = rem >> 2, dblk = rem & 3;
    int d = dblk * 256 + t;

    float A2[16];
    const float* ap = Alog + (size_t)d * NST;
    #pragma unroll
    for (int n = 0; n < 16; n++) A2[n] = -__expf(ap[n]) * LOG2E;
    float Dd = Dp[d];

    size_t NCH = (size_t)nb * 16384;
    size_t base = (size_t)c * NCH + ((size_t)b * 1024 + d) * 16;
    float h[16];
    #pragma unroll
    for (int n = 0; n < 16; n += 4)
        *(float4*)&h[n] = *(const float4*)&hin[base + n];

    for (int s = 0; s < TC; s++) {
        int q = c * TC + s;
        int l = dir ? (SEQ - 1 - q) : q;
        size_t row = (size_t)b * SEQ + l;
        float dt = dtb_[row * D_INNER + d];
        float u  = xcy[row * D_INNER + d];
        const float* dr = dbl + row * 48;
        float B[16], Cv[16];
        *(float4*)&B[0]   = *(const float4*)(dr + 16);
        *(float4*)&B[4]   = *(const float4*)(dr + 20);
        *(float4*)&B[8]   = *(const float4*)(dr + 24);
        *(float4*)&B[12]  = *(const float4*)(dr + 28);
        *(float4*)&Cv[0]  = *(const float4*)(dr + 32);
        *(float4*)&Cv[4]  = *(const float4*)(dr + 36);
        *(float4*)&Cv[8]  = *(const float4*)(dr + 40);
        *(float4*)&Cv[12] = *(const float4*)(dr + 44);
        float dtu = dt * u;
        #pragma unroll
        for (int n = 0; n < 16; n++)
            h[n] = h[n] * exp2f(A2[n] * dt) + dtu * B[n];

        float p0 = h[0]*Cv[0] + h[1]*Cv[1] + h[2]*Cv[2] + h[3]*Cv[3];
        float p1 = h[4]*Cv[4] + h[5]*Cv[5] + h[6]*Cv[6] + h[7]*Cv[7];
        float p2 = h[8]*Cv[8] + h[9]*Cv[9] + h[10]*Cv[10] + h[11]*Cv[11];
        float p3 = h[12]*Cv[12] + h[13]*Cv[13] + h[14]*Cv[14] + h[15]*Cv[15];
        float y = (p0 + p1) + (p2 + p3);

        float g = xz[row * (2 * D_INNER) + D_INNER + d];
        xcy[row * D_INNER + d] = (y + u * Dd) * g;
    }
}

// ---------------- host launch --------------------------------------------
extern "C" void kernel_launch(void* const* d_in, const int* in_sizes, int n_in,
                              void* d_out, int out_size, void* d_ws, size_t ws_size,
                              hipStream_t stream) {
    const float* input = (const float*)d_in[0];
    float* out = (float*)d_out;

    const size_t phfix = (size_t)2 * 256 * 16384 * 4;                        // 33.6 MB
    const size_t perb = (size_t)2048 * (256 + 2048 + 1024 + 48 + 1024) * 4;  // 36.0 MB
    int nb = 4;                      // cap 4: out_proj partials alias P/H (needs R*4096 B <= phfix)
    while (nb > 1 && phfix + (size_t)nb * perb > ws_size) nb >>= 1;
    const int NC = 256 / nb;
    const int TC = SEQ / NC;
    const int R = nb * SEQ;
    const int NCH = nb * 16384;

    float* P   = (float*)d_ws;                  // also out_proj partial buffer
    float* H   = P + (size_t)256 * 16384;
    float* xn  = H + (size_t)256 * 16384;
    float* xz  = xn  + (size_t)R * D_MODEL;
    float* xcy = xz  + (size_t)R * 2 * D_INNER;
    float* dbl = xcy + (size_t)R * D_INNER;
    float* dt  = dbl + (size_t)R * 48;

    for (int dir = 0; dir < 2; dir++) {
        int o = 1 + dir * 10;
        const float* nw   = (const float*)d_in[o + 0];
        const float* win  = (const float*)d_in[o + 1];
        const float* cw   = (const float*)d_in[o + 2];
        const float* cb   = (const float*)d_in[o + 3];
        const float* xp   = (const float*)d_in[o + 4];
        const float* dtw  = (const float*)d_in[o + 5];
        const float* dtbv = (const float*)d_in[o + 6];
        const float* Alog = (const float*)d_in[o + 7];
        const float* Dp   = (const float*)d_in[o + 8];
        const float* wout = (const float*)d_in[o + 9];

        for (int b0 = 0; b0 < 8; b0 += nb) {
            const float* xin = input + (size_t)b0 * SEQ * D_MODEL;
            float* cout = out + (size_t)b0 * SEQ * 2 * D_MODEL;

            rmsnorm_k<<<R, 256, 0, stream>>>(xin, nw, xn);
            gemm128<<<dim3(R / 128, 2 * D_INNER / 128), 256, 0, stream>>>(
                xn, win, xz, D_MODEL, 2 * D_INNER);
            conv_silu_k<<<(size_t)R * D_INNER / 256, 256, 0, stream>>>(
                xz, cw, cb, xcy, dir);
            hipMemsetAsync(dbl, 0, (size_t)R * 48 * 4, stream);
            gemm_xproj<<<dim3(R / 64, 4), 256, 0, stream>>>(
                xcy, xp, dbl, D_INNER, D_INNER / 4);
            dt_g_k<<<(size_t)R * D_INNER / 256, 256, 0, stream>>>(
                dbl, dtw, dtbv, dt, xz);
            scan_p1<<<NC * nb * 4, 256, 0, stream>>>(
                xcy, dt, dbl, Alog, P, H, nb, TC, dir);
            scan_p2<<<NCH / 256, 256, 0, stream>>>(P, H, NCH, NC);
            scan_p3<<<NC * nb * 4, 256, 0, stream>>>(
                xcy, dt, dbl, xz, Alog, Dp, H, nb, TC, dir);
            // out_proj: split-K=4 into P/H region (dead until next scan), then reduce
            gemm_osk<<<dim3(R / 128, 2, 4), 256, 0, stream>>>(xcy, wout, P, R);
            reduce_out_k<<<R * 64 / 256, 256, 0, stream>>>(
                P, xin, cout, R, dir * D_MODEL);
        }
    }
}

// Round 6
// 1394.990 us; speedup vs baseline: 4.0493x; 1.3004x over previous
//
#include <hip/hip_runtime.h>

typedef unsigned short u16;
typedef __bf16 bf16x8 __attribute__((ext_vector_type(8)));
typedef float f32x4 __attribute__((ext_vector_type(4)));

#define D_MODEL 256
#define D_INNER 1024
#define NST     16
#define SEQ     2048
#define LOG2E   1.4426950408889634f

static __device__ __forceinline__ float bf2f(u16 u) {
    union { float f; unsigned v; } x; x.v = ((unsigned)u) << 16; return x.f;
}
static __device__ __forceinline__ u16 f2bf(float f) {
    union { float f; unsigned u; } x; x.f = f;
    unsigned r = 0x7FFF + ((x.u >> 16) & 1);
    return (u16)((x.u + r) >> 16);
}

// ---- RMSNorm -> split-bf16 pair output: row = [256 hi | 256 lo] u16 ----
__global__ __launch_bounds__(256) void rmsnorm_k(const float* __restrict__ x,
                                                 const float* __restrict__ w,
                                                 u16* __restrict__ xnp) {
    int row = blockIdx.x, t = threadIdx.x;
    float v = x[(size_t)row * D_MODEL + t];
    float s = v * v;
    #pragma unroll
    for (int o = 32; o; o >>= 1) s += __shfl_xor(s, o, 64);
    __shared__ float red[4];
    if ((t & 63) == 0) red[t >> 6] = s;
    __syncthreads();
    float tot = red[0] + red[1] + red[2] + red[3];
    float scale = rsqrtf(tot * (1.0f / D_MODEL) + 1e-5f);
    float xv = v * scale * w[t];
    u16 hi = f2bf(xv);
    u16 lo = f2bf(xv - bf2f(hi));
    xnp[(size_t)row * 512 + t] = hi;
    xnp[(size_t)row * 512 + 256 + t] = lo;
}

// ---- weight split: src[N*K] f32 -> dst[N][2K] bf16 (hi | lo) -----------
__global__ __launch_bounds__(256) void wsplit_k(const float* __restrict__ src,
                                                u16* __restrict__ dst, int K) {
    int i = blockIdx.x * 256 + threadIdx.x;
    int n = i / K, k = i - n * K;
    float v = src[i];
    u16 hi = f2bf(v);
    u16 lo = f2bf(v - bf2f(hi));
    dst[(size_t)n * 2 * K + k] = hi;
    dst[(size_t)n * 2 * K + K + k] = lo;
}

// ---- split-bf16 MFMA GEMM over augmented K' = 3*KL ----------------------
// A_pair[M][2*KL] (hi|lo, row stride lda u16), W_pair[N][2*KL] (stride ldw)
// C fp32 [M][ldc] (+ zstride*blockIdx.z for split-K partials).
// Terms: t=0: Ah*Wh, t=1: Ah*Wl, t=2: Al*Wh. Tile 128x128, BK=64, 4 waves.
__global__ __launch_bounds__(256) void gemm_mfma(const u16* __restrict__ Ap, int lda,
                                                 const u16* __restrict__ Wp, int ldw,
                                                 float* __restrict__ C, int ldc,
                                                 int KL, int kslice, size_t zstride) {
    __shared__ u16 As[128][72];
    __shared__ u16 Ws[128][72];
    const int m0 = blockIdx.x * 128, n0 = blockIdx.y * 128;
    const int tid = threadIdx.x;
    const int wave = tid >> 6, lane = tid & 63;
    const int wm = (wave >> 1) * 64, wn = (wave & 1) * 64;
    const int lm = lane & 15, quad = lane >> 4;
    const int srow = tid >> 3, skk = (tid & 7) * 8;

    f32x4 acc[4][4] = {};

    const int kb0 = blockIdx.z * kslice;
    for (int k0 = kb0; k0 < kb0 + kslice; k0 += 64) {
        int t = k0 / KL;
        int ko = k0 - t * KL;
        int ka = ko + (t == 2 ? KL : 0);
        int kw = ko + (t == 1 ? KL : 0);
        #pragma unroll
        for (int p = 0; p < 4; p++) {
            int row = p * 32 + srow;
            *(uint4*)&As[row][skk] =
                *(const uint4*)(Ap + (size_t)(m0 + row) * lda + ka + skk);
            *(uint4*)&Ws[row][skk] =
                *(const uint4*)(Wp + (size_t)(n0 + row) * ldw + kw + skk);
        }
        __syncthreads();
        #pragma unroll
        for (int kk = 0; kk < 2; kk++) {
            bf16x8 af[4], bv[4];
            #pragma unroll
            for (int i = 0; i < 4; i++)
                af[i] = *(const bf16x8*)&As[wm + i * 16 + lm][kk * 32 + quad * 8];
            #pragma unroll
            for (int j = 0; j < 4; j++)
                bv[j] = *(const bf16x8*)&Ws[wn + j * 16 + lm][kk * 32 + quad * 8];
            #pragma unroll
            for (int i = 0; i < 4; i++)
                #pragma unroll
                for (int j = 0; j < 4; j++)
                    acc[i][j] = __builtin_amdgcn_mfma_f32_16x16x32_bf16(
                        af[i], bv[j], acc[i][j], 0, 0, 0);
        }
        __syncthreads();
    }

    float* Cz = C + zstride * blockIdx.z;
    #pragma unroll
    for (int i = 0; i < 4; i++)
        #pragma unroll
        for (int j = 0; j < 4; j++)
            #pragma unroll
            for (int r = 0; r < 4; r++) {
                int mrow = m0 + wm + i * 16 + quad * 4 + r;   // C/D: row=quad*4+reg
                int ncol = n0 + wn + j * 16 + lm;             //      col=lane&15
                Cz[(size_t)mrow * ldc + ncol] = acc[i][j][r];
            }
}

// ------ reduce 4 partials + residual -> out[m, coff + n] ------------------
__global__ __launch_bounds__(256) void reduce_out_k(const float* __restrict__ pbuf,
                                                    const float* __restrict__ res,
                                                    float* __restrict__ out,
                                                    int M, int coff) {
    int idx = blockIdx.x * 256 + threadIdx.x;     // over M*64 float4 groups
    int m = idx >> 6, n4 = (idx & 63) * 4;
    size_t e = (size_t)m * 256 + n4;
    size_t stride = (size_t)M * 256;
    float4 v = *(const float4*)(res + e);
    #pragma unroll
    for (int s = 0; s < 4; s++) {
        float4 p = *(const float4*)(pbuf + s * stride + e);
        v.x += p.x; v.y += p.y; v.z += p.z; v.w += p.w;
    }
    *(float4*)(out + (size_t)m * 512 + coff + n4) = v;
}

// ------- x_proj GEMM (fp32), split-K with atomic accumulate: N=48 --------
__global__ __launch_bounds__(256) void gemm_xproj(const float* __restrict__ A,
                                                  const float* __restrict__ W,
                                                  float* __restrict__ C,
                                                  int Kfull, int Kslice) {
    __shared__ float As[16][68];
    __shared__ float Ws[16][68];
    const int m0 = blockIdx.x * 64;
    const int kbase = blockIdx.y * Kslice;
    const int t = threadIdx.x;
    const int lr = t >> 2, lk = (t & 3) * 4;
    const int tm = (t & 15) * 4, tn = (t >> 4) * 4;
    float acc[4][4] = {};

    for (int k0 = kbase; k0 < kbase + Kslice; k0 += 16) {
        float4 av = *(const float4*)(A + (size_t)(m0 + lr) * Kfull + k0 + lk);
        float4 wv = make_float4(0.f, 0.f, 0.f, 0.f);
        if (lr < 48)
            wv = *(const float4*)(W + (size_t)lr * Kfull + k0 + lk);
        As[lk + 0][lr] = av.x; As[lk + 1][lr] = av.y;
        As[lk + 2][lr] = av.z; As[lk + 3][lr] = av.w;
        Ws[lk + 0][lr] = wv.x; Ws[lk + 1][lr] = wv.y;
        Ws[lk + 2][lr] = wv.z; Ws[lk + 3][lr] = wv.w;
        __syncthreads();
        #pragma unroll
        for (int k = 0; k < 16; k++) {
            float a4[4], b4[4];
            *(float4*)a4 = *(const float4*)(&As[k][tm]);
            *(float4*)b4 = *(const float4*)(&Ws[k][tn]);
            #pragma unroll
            for (int i = 0; i < 4; i++)
                #pragma unroll
                for (int j = 0; j < 4; j++)
                    acc[i][j] += a4[i] * b4[j];
        }
        __syncthreads();
    }

    #pragma unroll
    for (int i = 0; i < 4; i++) {
        int mrow = m0 + tm + i;
        #pragma unroll
        for (int j = 0; j < 4; j++) {
            int nc = tn + j;
            if (nc < 48)
                atomicAdd(&C[(size_t)mrow * 48 + nc], acc[i][j]);
        }
    }
}

// ---------------- depthwise causal conv (4 taps) + SiLU ------------------
__global__ __launch_bounds__(256) void conv_silu_k(const float* __restrict__ xi,
                                                   const float* __restrict__ cw,
                                                   const float* __restrict__ cb,
                                                   float* __restrict__ xc, int dir) {
    int idx = blockIdx.x * 256 + threadIdx.x;
    int d = idx & (D_INNER - 1);
    int bl = idx >> 10;
    int l = bl & (SEQ - 1);
    float acc = cb[d];
    #pragma unroll
    for (int j = 0; j < 4; j++) {
        int lo = (dir == 0) ? (l - 3 + j) : (l + 3 - j);
        if (lo >= 0 && lo < SEQ)
            acc += cw[d * 4 + j] * xi[(size_t)(bl - l + lo) * (2 * D_INNER) + d];
    }
    float s = acc / (1.0f + __expf(-acc));
    xc[(size_t)bl * D_INNER + d] = s;
}

// ------- dt = softplus(dt_low . dt_w + dt_b); g = silu(z) in place -------
__global__ __launch_bounds__(256) void dt_g_k(const float* __restrict__ dbl,
                                              const float* __restrict__ dtw,
                                              const float* __restrict__ dtb,
                                              float* __restrict__ dtout,
                                              float* __restrict__ xz) {
    int idx = blockIdx.x * 256 + threadIdx.x;
    int d = idx & (D_INNER - 1);
    size_t row = idx >> 10;
    const float* dr = dbl + row * 48;
    float acc = dtb[d];
    #pragma unroll
    for (int j = 0; j < 16; j++) acc += dr[j] * dtw[d * 16 + j];
    float dtv = (acc > 20.0f) ? acc : __logf(1.0f + __expf(acc));
    dtout[idx] = dtv;
    size_t zi = row * (2 * D_INNER) + D_INNER + d;
    float z = xz[zi];
    xz[zi] = z / (1.0f + __expf(-z));
}

// ---------------- scan phase 1: per-chunk H (h_in=0) and P ----------------
__global__ __launch_bounds__(256) void scan_p1(const float* __restrict__ xcy,
                                               const float* __restrict__ dtb_,
                                               const float* __restrict__ dbl,
                                               const float* __restrict__ Alog,
                                               float* __restrict__ P,
                                               float* __restrict__ H,
                                               int nb, int TC, int dir) {
    int t = threadIdx.x;
    int nblk4 = nb * 4;
    int c = blockIdx.x / nblk4;
    int rem = blockIdx.x - c * nblk4;
    int b = rem >> 2, dblk = rem & 3;
    int d = dblk * 256 + t;

    float A2[16];
    const float* ap = Alog + (size_t)d * NST;
    #pragma unroll
    for (int n = 0; n < 16; n++) A2[n] = -__expf(ap[n]) * LOG2E;
    float h[16] = {0,0,0,0,0,0,0,0,0,0,0,0,0,0,0,0};
    float S = 0.0f;

    for (int s = 0; s < TC; s++) {
        int q = c * TC + s;
        int l = dir ? (SEQ - 1 - q) : q;
        size_t row = (size_t)b * SEQ + l;
        float dt = dtb_[row * D_INNER + d];
        float u  = xcy[row * D_INNER + d];
        const float* dr = dbl + row * 48 + 16;
        float B[16];
        *(float4*)&B[0]  = *(const float4*)(dr);
        *(float4*)&B[4]  = *(const float4*)(dr + 4);
        *(float4*)&B[8]  = *(const float4*)(dr + 8);
        *(float4*)&B[12] = *(const float4*)(dr + 12);
        float dtu = dt * u;
        S += dt;
        #pragma unroll
        for (int n = 0; n < 16; n++)
            h[n] = h[n] * exp2f(A2[n] * dt) + dtu * B[n];
    }

    size_t NCH = (size_t)nb * 16384;
    size_t base = (size_t)c * NCH + ((size_t)b * 1024 + d) * 16;
    float Pv[16];
    #pragma unroll
    for (int n = 0; n < 16; n++) Pv[n] = exp2f(A2[n] * S);
    #pragma unroll
    for (int n = 0; n < 16; n += 4) {
        *(float4*)&H[base + n] = *(float4*)&h[n];
        *(float4*)&P[base + n] = *(float4*)&Pv[n];
    }
}

// ------- scan phase 2: combine chunk states; H repurposed as h_in --------
__global__ __launch_bounds__(256) void scan_p2(const float* __restrict__ P,
                                               float* __restrict__ H,
                                               int NCH, int NC) {
    size_t chain = (size_t)blockIdx.x * 256 + threadIdx.x;
    float h = 0.0f;
    for (int c = 0; c < NC; c++) {
        size_t i = (size_t)c * NCH + chain;
        float Hc = H[i], Pc = P[i];
        H[i] = h;
        h = Hc + Pc * h;
    }
}

// ---- scan phase 3: recurrence + y -> split-bf16 pair in xz x-half -------
__global__ __launch_bounds__(256) void scan_p3(const float* __restrict__ xcy,
                                               const float* __restrict__ dtb_,
                                               const float* __restrict__ dbl,
                                               float* __restrict__ xz,
                                               const float* __restrict__ Alog,
                                               const float* __restrict__ Dp,
                                               const float* __restrict__ hin,
                                               int nb, int TC, int dir) {
    int t = threadIdx.x;
    int nblk4 = nb * 4;
    int c = blockIdx.x / nblk4;
    int rem = blockIdx.x - c * nblk4;
    int b = rem >> 2, dblk = rem & 3;
    int d = dblk * 256 + t;

    float A2[16];
    const float* ap = Alog + (size_t)d * NST;
    #pragma unroll
    for (int n = 0; n < 16; n++) A2[n] = -__expf(ap[n]) * LOG2E;
    float Dd = Dp[d];

    size_t NCH = (size_t)nb * 16384;
    size_t base = (size_t)c * NCH + ((size_t)b * 1024 + d) * 16;
    float h[16];
    #pragma unroll
    for (int n = 0; n < 16; n += 4)
        *(float4*)&h[n] = *(const float4*)&hin[base + n];

    for (int s = 0; s < TC; s++) {
        int q = c * TC + s;
        int l = dir ? (SEQ - 1 - q) : q;
        size_t row = (size_t)b * SEQ + l;
        float dt = dtb_[row * D_INNER + d];
        float u  = xcy[row * D_INNER + d];
        const float* dr = dbl + row * 48;
        float B[16], Cv[16];
        *(float4*)&B[0]   = *(const float4*)(dr + 16);
        *(float4*)&B[4]   = *(const float4*)(dr + 20);
        *(float4*)&B[8]   = *(const float4*)(dr + 24);
        *(float4*)&B[12]  = *(const float4*)(dr + 28);
        *(float4*)&Cv[0]  = *(const float4*)(dr + 32);
        *(float4*)&Cv[4]  = *(const float4*)(dr + 36);
        *(float4*)&Cv[8]  = *(const float4*)(dr + 40);
        *(float4*)&Cv[12] = *(const float4*)(dr + 44);
        float dtu = dt * u;
        #pragma unroll
        for (int n = 0; n < 16; n++)
            h[n] = h[n] * exp2f(A2[n] * dt) + dtu * B[n];

        float p0 = h[0]*Cv[0] + h[1]*Cv[1] + h[2]*Cv[2] + h[3]*Cv[3];
        float p1 = h[4]*Cv[4] + h[5]*Cv[5] + h[6]*Cv[6] + h[7]*Cv[7];
        float p2 = h[8]*Cv[8] + h[9]*Cv[9] + h[10]*Cv[10] + h[11]*Cv[11];
        float p3 = h[12]*Cv[12] + h[13]*Cv[13] + h[14]*Cv[14] + h[15]*Cv[15];
        float g = xz[row * (2 * D_INNER) + D_INNER + d];   // silu(z)
        float y = ((p0 + p1) + (p2 + p3) + u * Dd) * g;

        // y split-bf16 pair into the dead xi half of xz: [1024 hi | 1024 lo]
        u16* yp = (u16*)(xz + row * (2 * D_INNER));
        u16 hi = f2bf(y);
        yp[d] = hi;
        yp[D_INNER + d] = f2bf(y - bf2f(hi));
    }
}

// ---------------- host launch --------------------------------------------
extern "C" void kernel_launch(void* const* d_in, const int* in_sizes, int n_in,
                              void* d_out, int out_size, void* d_ws, size_t ws_size,
                              hipStream_t stream) {
    const float* input = (const float*)d_in[0];
    float* out = (float*)d_out;

    const size_t phfix = (size_t)2 * 256 * 16384 * 4;                        // 33.6 MB
    const size_t perb  = (size_t)2048 * (256 + 2048 + 1024 + 48 + 1024) * 4; // 36.0 MB
    const size_t wspl  = (size_t)(2048 * 512 + 256 * 2048) * 2;              // 3.1 MB
    int nb = 4;                      // out_proj partials (R*4096 B) must fit P/H
    while (nb > 1 && phfix + (size_t)nb * perb + wspl > ws_size) nb >>= 1;
    const int NC = 256 / nb;
    const int TC = SEQ / NC;
    const int R = nb * SEQ;
    const int NCH = nb * 16384;

    float* P    = (float*)d_ws;                 // also out_proj partials (4 slices)
    float* H    = P + (size_t)256 * 16384;
    float* xnf  = H + (size_t)256 * 16384;      // region holds xn pair (u16)
    float* xz   = xnf + (size_t)R * D_MODEL;
    float* xcy  = xz  + (size_t)R * 2 * D_INNER;
    float* dbl  = xcy + (size_t)R * D_INNER;
    float* dt   = dbl + (size_t)R * 48;
    u16*  winp  = (u16*)(dt + (size_t)R * D_INNER);
    u16*  woutp = winp + (size_t)2048 * 512;
    u16*  xnp   = (u16*)xnf;

    for (int dir = 0; dir < 2; dir++) {
        int o = 1 + dir * 10;
        const float* nw   = (const float*)d_in[o + 0];
        const float* win  = (const float*)d_in[o + 1];
        const float* cw   = (const float*)d_in[o + 2];
        const float* cb   = (const float*)d_in[o + 3];
        const float* xp   = (const float*)d_in[o + 4];
        const float* dtw  = (const float*)d_in[o + 5];
        const float* dtbv = (const float*)d_in[o + 6];
        const float* Alog = (const float*)d_in[o + 7];
        const float* Dp   = (const float*)d_in[o + 8];
        const float* wout = (const float*)d_in[o + 9];

        wsplit_k<<<2048 * 256 / 256, 256, 0, stream>>>(win, winp, D_MODEL);
        wsplit_k<<<256 * 1024 / 256, 256, 0, stream>>>(wout, woutp, D_INNER);

        for (int b0 = 0; b0 < 8; b0 += nb) {
            const float* xin = input + (size_t)b0 * SEQ * D_MODEL;
            float* cout = out + (size_t)b0 * SEQ * 2 * D_MODEL;

            rmsnorm_k<<<R, 256, 0, stream>>>(xin, nw, xnp);
            // in_proj: C[R,2048] = xn * win^T, split-bf16, K'=768
            gemm_mfma<<<dim3(R / 128, 16, 1), 256, 0, stream>>>(
                xnp, 512, winp, 512, xz, 2 * D_INNER, D_MODEL, 3 * D_MODEL, 0);
            conv_silu_k<<<(size_t)R * D_INNER / 256, 256, 0, stream>>>(
                xz, cw, cb, xcy, dir);
            hipMemsetAsync(dbl, 0, (size_t)R * 48 * 4, stream);
            gemm_xproj<<<dim3(R / 64, 4), 256, 0, stream>>>(
                xcy, xp, dbl, D_INNER, D_INNER / 4);
            dt_g_k<<<(size_t)R * D_INNER / 256, 256, 0, stream>>>(
                dbl, dtw, dtbv, dt, xz);
            scan_p1<<<NC * nb * 4, 256, 0, stream>>>(
                xcy, dt, dbl, Alog, P, H, nb, TC, dir);
            scan_p2<<<NCH / 256, 256, 0, stream>>>(P, H, NCH, NC);
            scan_p3<<<NC * nb * 4, 256, 0, stream>>>(
                xcy, dt, dbl, xz, Alog, Dp, H, nb, TC, dir);
            // out_proj: y_pair (in xz) * wout^T, K'=3072, split-K=4 -> P partials
            gemm_mfma<<<dim3(R / 128, 2, 4), 256, 0, stream>>>(
                (const u16*)xz, 4096, woutp, 2048, P, 256, D_INNER, 768,
                (size_t)R * 256);
            reduce_out_k<<<R * 64 / 256, 256, 0, stream>>>(
                P, xin, cout, R, dir * D_MODEL);
        }
    }
}

// Round 7
// 1221.571 us; speedup vs baseline: 4.6241x; 1.1420x over previous
//
#include <hip/hip_runtime.h>

typedef unsigned short u16;
typedef __bf16 bf16x8 __attribute__((ext_vector_type(8)));
typedef float f32x4 __attribute__((ext_vector_type(4)));

#define D_MODEL 256
#define D_INNER 1024
#define NST     16
#define SEQ     2048
#define LOG2E   1.4426950408889634f

static __device__ __forceinline__ float bf2f(u16 u) {
    union { float f; unsigned v; } x; x.v = ((unsigned)u) << 16; return x.f;
}
static __device__ __forceinline__ u16 f2bf(float f) {
    union { float f; unsigned u; } x; x.f = f;
    unsigned r = 0x7FFF + ((x.u >> 16) & 1);
    return (u16)((x.u + r) >> 16);
}

// ---- RMSNorm -> split-bf16 pair output: row = [256 hi | 256 lo] u16 ----
__global__ __launch_bounds__(256) void rmsnorm_k(const float* __restrict__ x,
                                                 const float* __restrict__ w,
                                                 u16* __restrict__ xnp) {
    int row = blockIdx.x, t = threadIdx.x;
    float v = x[(size_t)row * D_MODEL + t];
    float s = v * v;
    #pragma unroll
    for (int o = 32; o; o >>= 1) s += __shfl_xor(s, o, 64);
    __shared__ float red[4];
    if ((t & 63) == 0) red[t >> 6] = s;
    __syncthreads();
    float tot = red[0] + red[1] + red[2] + red[3];
    float scale = rsqrtf(tot * (1.0f / D_MODEL) + 1e-5f);
    float xv = v * scale * w[t];
    u16 hi = f2bf(xv);
    u16 lo = f2bf(xv - bf2f(hi));
    xnp[(size_t)row * 512 + t] = hi;
    xnp[(size_t)row * 512 + 256 + t] = lo;
}

// ---- weight split: src[N*K] f32 -> dst[N][2K] bf16 (hi | lo) -----------
__global__ __launch_bounds__(256) void wsplit_k(const float* __restrict__ src,
                                                u16* __restrict__ dst, int K) {
    int i = blockIdx.x * 256 + threadIdx.x;
    int n = i / K, k = i - n * K;
    float v = src[i];
    u16 hi = f2bf(v);
    u16 lo = f2bf(v - bf2f(hi));
    dst[(size_t)n * 2 * K + k] = hi;
    dst[(size_t)n * 2 * K + K + k] = lo;
}

// ---- split-bf16 MFMA GEMM over augmented K' = 3*KL ----------------------
// A_pair[M][2*KL] (hi|lo, row stride lda u16), W_pair[N][2*KL] (stride ldw)
// C fp32 [M][ldc] (+ zstride*blockIdx.z). Nreal: valid W rows / C cols.
// Terms: t=0: Ah*Wh, t=1: Ah*Wl, t=2: Al*Wh. Tile 128x128, BK=64, 4 waves.
__global__ __launch_bounds__(256) void gemm_mfma(const u16* __restrict__ Ap, int lda,
                                                 const u16* __restrict__ Wp, int ldw,
                                                 float* __restrict__ C, int ldc,
                                                 int KL, int kslice, size_t zstride,
                                                 int Nreal) {
    __shared__ u16 As[128][72];
    __shared__ u16 Ws[128][72];
    const int m0 = blockIdx.x * 128, n0 = blockIdx.y * 128;
    const int tid = threadIdx.x;
    const int wave = tid >> 6, lane = tid & 63;
    const int wm = (wave >> 1) * 64, wn = (wave & 1) * 64;
    const int lm = lane & 15, quad = lane >> 4;
    const int srow = tid >> 3, skk = (tid & 7) * 8;

    f32x4 acc[4][4] = {};

    const int kb0 = blockIdx.z * kslice;
    for (int k0 = kb0; k0 < kb0 + kslice; k0 += 64) {
        int t = k0 / KL;
        int ko = k0 - t * KL;
        int ka = ko + (t == 2 ? KL : 0);
        int kw = ko + (t == 1 ? KL : 0);
        #pragma unroll
        for (int p = 0; p < 4; p++) {
            int row = p * 32 + srow;
            *(uint4*)&As[row][skk] =
                *(const uint4*)(Ap + (size_t)(m0 + row) * lda + ka + skk);
            uint4 wv = {0u, 0u, 0u, 0u};
            if (n0 + row < Nreal)
                wv = *(const uint4*)(Wp + (size_t)(n0 + row) * ldw + kw + skk);
            *(uint4*)&Ws[row][skk] = wv;
        }
        __syncthreads();
        #pragma unroll
        for (int kk = 0; kk < 2; kk++) {
            bf16x8 af[4], bv[4];
            #pragma unroll
            for (int i = 0; i < 4; i++)
                af[i] = *(const bf16x8*)&As[wm + i * 16 + lm][kk * 32 + quad * 8];
            #pragma unroll
            for (int j = 0; j < 4; j++)
                bv[j] = *(const bf16x8*)&Ws[wn + j * 16 + lm][kk * 32 + quad * 8];
            #pragma unroll
            for (int i = 0; i < 4; i++)
                #pragma unroll
                for (int j = 0; j < 4; j++)
                    acc[i][j] = __builtin_amdgcn_mfma_f32_16x16x32_bf16(
                        af[i], bv[j], acc[i][j], 0, 0, 0);
        }
        __syncthreads();
    }

    float* Cz = C + zstride * blockIdx.z;
    #pragma unroll
    for (int i = 0; i < 4; i++)
        #pragma unroll
        for (int j = 0; j < 4; j++)
            #pragma unroll
            for (int r = 0; r < 4; r++) {
                int mrow = m0 + wm + i * 16 + quad * 4 + r;   // C/D: row=quad*4+reg
                int ncol = n0 + wn + j * 16 + lm;             //      col=lane&15
                if (ncol < Nreal)
                    Cz[(size_t)mrow * ldc + ncol] = acc[i][j][r];
            }
}

// ------ reduce 8 x_proj partials -> dbl[R*48] -----------------------------
__global__ __launch_bounds__(256) void reduce_dbl_k(const float* __restrict__ pbuf,
                                                    float* __restrict__ dbl,
                                                    size_t RS) {
    size_t e = (size_t)blockIdx.x * 256 + threadIdx.x;
    float v = 0.0f;
    #pragma unroll
    for (int z = 0; z < 8; z++) v += pbuf[z * RS + e];
    dbl[e] = v;
}

// ------ reduce 4 out_proj partials + residual -> out[m, coff + n] ---------
__global__ __launch_bounds__(256) void reduce_out_k(const float* __restrict__ pbuf,
                                                    const float* __restrict__ res,
                                                    float* __restrict__ out,
                                                    int M, int coff) {
    int idx = blockIdx.x * 256 + threadIdx.x;
    int m = idx >> 6, n4 = (idx & 63) * 4;
    size_t e = (size_t)m * 256 + n4;
    size_t stride = (size_t)M * 256;
    float4 v = *(const float4*)(res + e);
    #pragma unroll
    for (int s = 0; s < 4; s++) {
        float4 p = *(const float4*)(pbuf + s * stride + e);
        v.x += p.x; v.y += p.y; v.z += p.z; v.w += p.w;
    }
    *(float4*)(out + (size_t)m * 512 + coff + n4) = v;
}

// ---- depthwise causal conv + SiLU; out = split-bf16 pair ----------------
// thread: 4 consecutive l at fixed d; out row = [1024 hi | 1024 lo] u16.
__global__ __launch_bounds__(256) void conv_silu_k(const float* __restrict__ xz,
                                                   const float* __restrict__ cw,
                                                   const float* __restrict__ cb,
                                                   u16* __restrict__ xcp, int dir) {
    int bx = blockIdx.x;
    int dgrp = bx & 3;
    int rowgrp = bx >> 2;
    int l0 = (rowgrp & (SEQ / 4 - 1)) * 4;
    int b = rowgrp >> 9;                       // rowgrp / (SEQ/4)
    int d = dgrp * 256 + threadIdx.x;

    int base = dir ? l0 : (l0 - 3);
    float x[7];
    #pragma unroll
    for (int i = 0; i < 7; i++) {
        int lr = base + i;
        x[i] = (lr >= 0 && lr < SEQ)
             ? xz[((size_t)b * SEQ + lr) * (2 * D_INNER) + d] : 0.0f;
    }
    float w0 = cw[d * 4 + 0], w1 = cw[d * 4 + 1];
    float w2 = cw[d * 4 + 2], w3 = cw[d * 4 + 3];
    float bias = cb[d];

    #pragma unroll
    for (int li = 0; li < 4; li++) {
        float acc;
        if (dir == 0)
            acc = bias + w0 * x[li] + w1 * x[li + 1] + w2 * x[li + 2] + w3 * x[li + 3];
        else
            acc = bias + w3 * x[li] + w2 * x[li + 1] + w1 * x[li + 2] + w0 * x[li + 3];
        float s = acc / (1.0f + __expf(-acc));
        u16 hi = f2bf(s);
        u16 lo = f2bf(s - bf2f(hi));
        size_t row = (size_t)b * SEQ + l0 + li;
        xcp[row * 2048 + d] = hi;
        xcp[row * 2048 + D_INNER + d] = lo;
    }
}

// ---- scan phase 1: per-chunk H (h_in=0) and P; dt computed inline -------
__global__ __launch_bounds__(256) void scan_p1(const u16* __restrict__ xcp,
                                               const float* __restrict__ dbl,
                                               const float* __restrict__ dtw,
                                               const float* __restrict__ dtb,
                                               const float* __restrict__ Alog,
                                               float* __restrict__ P,
                                               float* __restrict__ H,
                                               int nb, int TC, int dir) {
    int t = threadIdx.x;
    int nblk4 = nb * 4;
    int c = blockIdx.x / nblk4;
    int rem = blockIdx.x - c * nblk4;
    int b = rem >> 2, dblk = rem & 3;
    int d = dblk * 256 + t;

    float A2[16], wdt[16];
    const float* ap = Alog + (size_t)d * NST;
    const float* wp = dtw + (size_t)d * NST;
    #pragma unroll
    for (int n = 0; n < 16; n++) { A2[n] = -__expf(ap[n]) * LOG2E; wdt[n] = wp[n]; }
    float bdt = dtb[d];
    float h[16] = {0,0,0,0,0,0,0,0,0,0,0,0,0,0,0,0};
    float S = 0.0f;

    for (int s = 0; s < TC; s++) {
        int q = c * TC + s;
        int l = dir ? (SEQ - 1 - q) : q;
        size_t row = (size_t)b * SEQ + l;
        const float* dr = dbl + row * 48;
        float dl[16], B[16];
        #pragma unroll
        for (int n = 0; n < 16; n += 4) {
            *(float4*)&dl[n] = *(const float4*)(dr + n);
            *(float4*)&B[n]  = *(const float4*)(dr + 16 + n);
        }
        float u = bf2f(xcp[row * 2048 + d]) + bf2f(xcp[row * 2048 + D_INNER + d]);
        float acc = bdt;
        #pragma unroll
        for (int n = 0; n < 16; n++) acc += dl[n] * wdt[n];
        float dt = (acc > 20.0f) ? acc : __logf(1.0f + __expf(acc));
        float dtu = dt * u;
        S += dt;
        #pragma unroll
        for (int n = 0; n < 16; n++)
            h[n] = h[n] * exp2f(A2[n] * dt) + dtu * B[n];
    }

    size_t NCH = (size_t)nb * 16384;
    size_t base = (size_t)c * NCH + ((size_t)b * 1024 + d) * 16;
    float Pv[16];
    #pragma unroll
    for (int n = 0; n < 16; n++) Pv[n] = exp2f(A2[n] * S);
    #pragma unroll
    for (int n = 0; n < 16; n += 4) {
        *(float4*)&H[base + n] = *(float4*)&h[n];
        *(float4*)&P[base + n] = *(float4*)&Pv[n];
    }
}

// ------- scan phase 2: combine chunk states; H repurposed as h_in --------
__global__ __launch_bounds__(256) void scan_p2(const float* __restrict__ P,
                                               float* __restrict__ H,
                                               int NCH, int NC) {
    size_t chain = (size_t)blockIdx.x * 256 + threadIdx.x;
    float h = 0.0f;
    for (int c = 0; c < NC; c++) {
        size_t i = (size_t)c * NCH + chain;
        float Hc = H[i], Pc = P[i];
        H[i] = h;
        h = Hc + Pc * h;
    }
}

// ---- scan phase 3: recurrence + silu(z) + y -> split-bf16 pair ----------
__global__ __launch_bounds__(256) void scan_p3(const u16* __restrict__ xcp,
                                               const float* __restrict__ dbl,
                                               const float* __restrict__ dtw,
                                               const float* __restrict__ dtb,
                                               float* __restrict__ xz,
                                               const float* __restrict__ Alog,
                                               const float* __restrict__ Dp,
                                               const float* __restrict__ hin,
                                               int nb, int TC, int dir) {
    int t = threadIdx.x;
    int nblk4 = nb * 4;
    int c = blockIdx.x / nblk4;
    int rem = blockIdx.x - c * nblk4;
    int b = rem >> 2, dblk = rem & 3;
    int d = dblk * 256 + t;

    float A2[16], wdt[16];
    const float* ap = Alog + (size_t)d * NST;
    const float* wp = dtw + (size_t)d * NST;
    #pragma unroll
    for (int n = 0; n < 16; n++) { A2[n] = -__expf(ap[n]) * LOG2E; wdt[n] = wp[n]; }
    float bdt = dtb[d];
    float Dd = Dp[d];

    size_t NCH = (size_t)nb * 16384;
    size_t base = (size_t)c * NCH + ((size_t)b * 1024 + d) * 16;
    float h[16];
    #pragma unroll
    for (int n = 0; n < 16; n += 4)
        *(float4*)&h[n] = *(const float4*)&hin[base + n];

    for (int s = 0; s < TC; s++) {
        int q = c * TC + s;
        int l = dir ? (SEQ - 1 - q) : q;
        size_t row = (size_t)b * SEQ + l;
        const float* dr = dbl + row * 48;
        float dl[16], B[16], Cv[16];
        #pragma unroll
        for (int n = 0; n < 16; n += 4) {
            *(float4*)&dl[n] = *(const float4*)(dr + n);
            *(float4*)&B[n]  = *(const float4*)(dr + 16 + n);
            *(float4*)&Cv[n] = *(const float4*)(dr + 32 + n);
        }
        float u = bf2f(xcp[row * 2048 + d]) + bf2f(xcp[row * 2048 + D_INNER + d]);
        float acc = bdt;
        #pragma unroll
        for (int n = 0; n < 16; n++) acc += dl[n] * wdt[n];
        float dt = (acc > 20.0f) ? acc : __logf(1.0f + __expf(acc));
        float dtu = dt * u;
        #pragma unroll
        for (int n = 0; n < 16; n++)
            h[n] = h[n] * exp2f(A2[n] * dt) + dtu * B[n];

        float p0 = h[0]*Cv[0] + h[1]*Cv[1] + h[2]*Cv[2] + h[3]*Cv[3];
        float p1 = h[4]*Cv[4] + h[5]*Cv[5] + h[6]*Cv[6] + h[7]*Cv[7];
        float p2 = h[8]*Cv[8] + h[9]*Cv[9] + h[10]*Cv[10] + h[11]*Cv[11];
        float p3 = h[12]*Cv[12] + h[13]*Cv[13] + h[14]*Cv[14] + h[15]*Cv[15];

        float z = xz[row * (2 * D_INNER) + D_INNER + d];
        float g = z / (1.0f + __expf(-z));
        float y = ((p0 + p1) + (p2 + p3) + u * Dd) * g;

        u16* yp = (u16*)(xz + row * (2 * D_INNER));
        u16 hi = f2bf(y);
        yp[d] = hi;
        yp[D_INNER + d] = f2bf(y - bf2f(hi));
    }
}

// ---------------- host launch --------------------------------------------
extern "C" void kernel_launch(void* const* d_in, const int* in_sizes, int n_in,
                              void* d_out, int out_size, void* d_ws, size_t ws_size,
                              hipStream_t stream) {
    const float* input = (const float*)d_in[0];
    float* out = (float*)d_out;

    const size_t phfix = (size_t)2 * 256 * 16384 * 4;                 // 33.6 MB
    const size_t perb  = (size_t)2048 * (256 + 2048 + 1024 + 48) * 4; // 27.7 MB
    const size_t wspl  = (size_t)(2048 * 512 + 256 * 2048 + 48 * 2048) * 2;
    int nb = 4;                       // out_proj partials (R*4096 B) fit P+H
    while (nb > 1 && phfix + (size_t)nb * perb + wspl > ws_size) nb >>= 1;
    const int NC = 256 / nb;
    const int TC = SEQ / NC;
    const int R = nb * SEQ;
    const int NCH = nb * 16384;

    float* P    = (float*)d_ws;        // xproj partials / out_proj partials / scan P
    float* H    = P + (size_t)256 * 16384;
    float* xnf  = H + (size_t)256 * 16384;      // xn pair (u16) region
    float* xz   = xnf + (size_t)R * D_MODEL;
    float* xcyf = xz  + (size_t)R * 2 * D_INNER; // xc pair (u16) region
    float* dbl  = xcyf + (size_t)R * D_INNER;
    u16*  winp  = (u16*)(dbl + (size_t)R * 48);
    u16*  woutp = winp + (size_t)2048 * 512;
    u16*  xpp   = woutp + (size_t)256 * 2048;
    u16*  xnp   = (u16*)xnf;
    u16*  xcp   = (u16*)xcyf;

    for (int dir = 0; dir < 2; dir++) {
        int o = 1 + dir * 10;
        const float* nw   = (const float*)d_in[o + 0];
        const float* win  = (const float*)d_in[o + 1];
        const float* cw   = (const float*)d_in[o + 2];
        const float* cb   = (const float*)d_in[o + 3];
        const float* xp   = (const float*)d_in[o + 4];
        const float* dtw  = (const float*)d_in[o + 5];
        const float* dtbv = (const float*)d_in[o + 6];
        const float* Alog = (const float*)d_in[o + 7];
        const float* Dp   = (const float*)d_in[o + 8];
        const float* wout = (const float*)d_in[o + 9];

        wsplit_k<<<2048 * 256 / 256, 256, 0, stream>>>(win, winp, D_MODEL);
        wsplit_k<<<256 * 1024 / 256, 256, 0, stream>>>(wout, woutp, D_INNER);
        wsplit_k<<<48 * 1024 / 256, 256, 0, stream>>>(xp, xpp, D_INNER);

        for (int b0 = 0; b0 < 8; b0 += nb) {
            const float* xin = input + (size_t)b0 * SEQ * D_MODEL;
            float* cout = out + (size_t)b0 * SEQ * 2 * D_MODEL;

            rmsnorm_k<<<R, 256, 0, stream>>>(xin, nw, xnp);
            // in_proj: xz[R,2048] = xn * win^T, K'=768
            gemm_mfma<<<dim3(R / 128, 16, 1), 256, 0, stream>>>(
                xnp, 512, winp, 512, xz, 2 * D_INNER, D_MODEL, 3 * D_MODEL, 0,
                2 * D_INNER);
            conv_silu_k<<<R, 256, 0, stream>>>(xz, cw, cb, xcp, dir);
            // x_proj: dbl partials[8][R,48] = xc * xp^T, K'=3072, split-K=8
            gemm_mfma<<<dim3(R / 128, 1, 8), 256, 0, stream>>>(
                xcp, 2048, xpp, 2048, P, 48, D_INNER, 384, (size_t)R * 48, 48);
            reduce_dbl_k<<<R * 48 / 256, 256, 0, stream>>>(P, dbl, (size_t)R * 48);
            scan_p1<<<NC * nb * 4, 256, 0, stream>>>(
                xcp, dbl, dtw, dtbv, Alog, P, H, nb, TC, dir);
            scan_p2<<<NCH / 256, 256, 0, stream>>>(P, H, NCH, NC);
            scan_p3<<<NC * nb * 4, 256, 0, stream>>>(
                xcp, dbl, dtw, dtbv, xz, Alog, Dp, H, nb, TC, dir);
            // out_proj: y_pair (xz xi half) * wout^T, K'=3072, split-K=4
            gemm_mfma<<<dim3(R / 128, 2, 4), 256, 0, stream>>>(
                (const u16*)xz, 4096, woutp, 2048, P, 256, D_INNER, 768,
                (size_t)R * 256, 256);
            reduce_out_k<<<R * 64 / 256, 256, 0, stream>>>(
                P, xin, cout, R, dir * D_MODEL);
        }
    }
}

// Round 8
// 1029.760 us; speedup vs baseline: 5.4854x; 1.1863x over previous
//
#include <hip/hip_runtime.h>

typedef unsigned short u16;
typedef __bf16 bf16x8 __attribute__((ext_vector_type(8)));
typedef float f32x4 __attribute__((ext_vector_type(4)));

#define D_MODEL 256
#define D_INNER 1024
#define NST     16
#define SEQ     2048
#define LOG2E   1.4426950408889634f

struct TrueT  { static constexpr bool value = true;  };
struct FalseT { static constexpr bool value = false; };

static __device__ __forceinline__ float bf2f(u16 u) {
    union { float f; unsigned v; } x; x.v = ((unsigned)u) << 16; return x.f;
}
static __device__ __forceinline__ u16 f2bf(float f) {
    union { float f; unsigned u; } x; x.f = f;
    unsigned r = 0x7FFF + ((x.u >> 16) & 1);
    return (u16)((x.u + r) >> 16);
}

// dA[n] = e1^(n+1), n=0..15, via binary decomposition (16 muls, depth ~5)
static __device__ __forceinline__ void dA_pow(float e1, float* dA) {
    float e2 = e1 * e1, e3 = e2 * e1, e4 = e2 * e2;
    float e8 = e4 * e4, e12 = e8 * e4;
    dA[0] = e1;       dA[1] = e2;       dA[2] = e3;       dA[3] = e4;
    dA[4] = e4 * e1;  dA[5] = e4 * e2;  dA[6] = e4 * e3;  dA[7] = e8;
    dA[8] = e8 * e1;  dA[9] = e8 * e2;  dA[10] = e8 * e3; dA[11] = e12;
    dA[12] = e12 * e1; dA[13] = e12 * e2; dA[14] = e12 * e3; dA[15] = e8 * e8;
}

// ---- RMSNorm -> split-bf16 pair output: row = [256 hi | 256 lo] u16 ----
__global__ __launch_bounds__(256) void rmsnorm_k(const float* __restrict__ x,
                                                 const float* __restrict__ w,
                                                 u16* __restrict__ xnp) {
    int row = blockIdx.x, t = threadIdx.x;
    float v = x[(size_t)row * D_MODEL + t];
    float s = v * v;
    #pragma unroll
    for (int o = 32; o; o >>= 1) s += __shfl_xor(s, o, 64);
    __shared__ float red[4];
    if ((t & 63) == 0) red[t >> 6] = s;
    __syncthreads();
    float tot = red[0] + red[1] + red[2] + red[3];
    float scale = rsqrtf(tot * (1.0f / D_MODEL) + 1e-5f);
    float xv = v * scale * w[t];
    u16 hi = f2bf(xv);
    u16 lo = f2bf(xv - bf2f(hi));
    xnp[(size_t)row * 512 + t] = hi;
    xnp[(size_t)row * 512 + 256 + t] = lo;
}

// ---- weight split: src[N*K] f32 -> dst[N][2K] bf16 (hi | lo) -----------
__global__ __launch_bounds__(256) void wsplit_k(const float* __restrict__ src,
                                                u16* __restrict__ dst, int K) {
    int i = blockIdx.x * 256 + threadIdx.x;
    int n = i / K, k = i - n * K;
    float v = src[i];
    u16 hi = f2bf(v);
    u16 lo = f2bf(v - bf2f(hi));
    dst[(size_t)n * 2 * K + k] = hi;
    dst[(size_t)n * 2 * K + K + k] = lo;
}

// ---- split-bf16 MFMA GEMM over augmented K' = 3*KL ----------------------
// Terms: t=0: Ah*Wh, t=1: Ah*Wl, t=2: Al*Wh. Tile 128x128, BK=64, 4 waves.
__global__ __launch_bounds__(256) void gemm_mfma(const u16* __restrict__ Ap, int lda,
                                                 const u16* __restrict__ Wp, int ldw,
                                                 float* __restrict__ C, int ldc,
                                                 int KL, int kslice, size_t zstride,
                                                 int Nreal) {
    __shared__ u16 As[128][72];
    __shared__ u16 Ws[128][72];
    const int m0 = blockIdx.x * 128, n0 = blockIdx.y * 128;
    const int tid = threadIdx.x;
    const int wave = tid >> 6, lane = tid & 63;
    const int wm = (wave >> 1) * 64, wn = (wave & 1) * 64;
    const int lm = lane & 15, quad = lane >> 4;
    const int srow = tid >> 3, skk = (tid & 7) * 8;

    f32x4 acc[4][4] = {};

    const int kb0 = blockIdx.z * kslice;
    for (int k0 = kb0; k0 < kb0 + kslice; k0 += 64) {
        int t = k0 / KL;
        int ko = k0 - t * KL;
        int ka = ko + (t == 2 ? KL : 0);
        int kw = ko + (t == 1 ? KL : 0);
        #pragma unroll
        for (int p = 0; p < 4; p++) {
            int row = p * 32 + srow;
            *(uint4*)&As[row][skk] =
                *(const uint4*)(Ap + (size_t)(m0 + row) * lda + ka + skk);
            uint4 wv = {0u, 0u, 0u, 0u};
            if (n0 + row < Nreal)
                wv = *(const uint4*)(Wp + (size_t)(n0 + row) * ldw + kw + skk);
            *(uint4*)&Ws[row][skk] = wv;
        }
        __syncthreads();
        #pragma unroll
        for (int kk = 0; kk < 2; kk++) {
            bf16x8 af[4], bv[4];
            #pragma unroll
            for (int i = 0; i < 4; i++)
                af[i] = *(const bf16x8*)&As[wm + i * 16 + lm][kk * 32 + quad * 8];
            #pragma unroll
            for (int j = 0; j < 4; j++)
                bv[j] = *(const bf16x8*)&Ws[wn + j * 16 + lm][kk * 32 + quad * 8];
            #pragma unroll
            for (int i = 0; i < 4; i++)
                #pragma unroll
                for (int j = 0; j < 4; j++)
                    acc[i][j] = __builtin_amdgcn_mfma_f32_16x16x32_bf16(
                        af[i], bv[j], acc[i][j], 0, 0, 0);
        }
        __syncthreads();
    }

    float* Cz = C + zstride * blockIdx.z;
    #pragma unroll
    for (int i = 0; i < 4; i++)
        #pragma unroll
        for (int j = 0; j < 4; j++)
            #pragma unroll
            for (int r = 0; r < 4; r++) {
                int mrow = m0 + wm + i * 16 + quad * 4 + r;   // C/D: row=quad*4+reg
                int ncol = n0 + wn + j * 16 + lm;             //      col=lane&15
                if (ncol < Nreal)
                    Cz[(size_t)mrow * ldc + ncol] = acc[i][j][r];
            }
}

// ------ reduce 8 x_proj partials -> dbl[R*48] -----------------------------
__global__ __launch_bounds__(256) void reduce_dbl_k(const float* __restrict__ pbuf,
                                                    float* __restrict__ dbl,
                                                    size_t RS) {
    size_t e = (size_t)blockIdx.x * 256 + threadIdx.x;
    float v = 0.0f;
    #pragma unroll
    for (int z = 0; z < 8; z++) v += pbuf[z * RS + e];
    dbl[e] = v;
}

// ------ reduce 4 out_proj partials + residual -> out[m, coff + n] ---------
__global__ __launch_bounds__(256) void reduce_out_k(const float* __restrict__ pbuf,
                                                    const float* __restrict__ res,
                                                    float* __restrict__ out,
                                                    int M, int coff) {
    int idx = blockIdx.x * 256 + threadIdx.x;
    int m = idx >> 6, n4 = (idx & 63) * 4;
    size_t e = (size_t)m * 256 + n4;
    size_t stride = (size_t)M * 256;
    float4 v = *(const float4*)(res + e);
    #pragma unroll
    for (int s = 0; s < 4; s++) {
        float4 p = *(const float4*)(pbuf + s * stride + e);
        v.x += p.x; v.y += p.y; v.z += p.z; v.w += p.w;
    }
    *(float4*)(out + (size_t)m * 512 + coff + n4) = v;
}

// ---- depthwise causal conv + SiLU; out = split-bf16 pair ----------------
__global__ __launch_bounds__(256) void conv_silu_k(const float* __restrict__ xz,
                                                   const float* __restrict__ cw,
                                                   const float* __restrict__ cb,
                                                   u16* __restrict__ xcp, int dir) {
    int bx = blockIdx.x;
    int dgrp = bx & 3;
    int rowgrp = bx >> 2;
    int l0 = (rowgrp & (SEQ / 4 - 1)) * 4;
    int b = rowgrp >> 9;
    int d = dgrp * 256 + threadIdx.x;

    int base = dir ? l0 : (l0 - 3);
    float x[7];
    #pragma unroll
    for (int i = 0; i < 7; i++) {
        int lr = base + i;
        x[i] = (lr >= 0 && lr < SEQ)
             ? xz[((size_t)b * SEQ + lr) * (2 * D_INNER) + d] : 0.0f;
    }
    float w0 = cw[d * 4 + 0], w1 = cw[d * 4 + 1];
    float w2 = cw[d * 4 + 2], w3 = cw[d * 4 + 3];
    float bias = cb[d];

    #pragma unroll
    for (int li = 0; li < 4; li++) {
        float acc;
        if (dir == 0)
            acc = bias + w0 * x[li] + w1 * x[li + 1] + w2 * x[li + 2] + w3 * x[li + 3];
        else
            acc = bias + w3 * x[li] + w2 * x[li + 1] + w1 * x[li + 2] + w0 * x[li + 3];
        float s = acc / (1.0f + __expf(-acc));
        u16 hi = f2bf(s);
        u16 lo = f2bf(s - bf2f(hi));
        size_t row = (size_t)b * SEQ + l0 + li;
        xcp[row * 2048 + d] = hi;
        xcp[row * 2048 + D_INNER + d] = lo;
    }
}

// ---- scan phase 1: per-chunk H (h_in=0) and P; dt inline; A-power dA ----
__global__ __launch_bounds__(256) void scan_p1(const u16* __restrict__ xcp,
                                               const float* __restrict__ dbl,
                                               const float* __restrict__ dtw,
                                               const float* __restrict__ dtb,
                                               const float* __restrict__ Alog,
                                               float* __restrict__ P,
                                               float* __restrict__ H,
                                               int nb, int TC, int dir) {
    int t = threadIdx.x;
    int nblk4 = nb * 4;
    int c = blockIdx.x / nblk4;
    int rem = blockIdx.x - c * nblk4;
    int b = rem >> 2, dblk = rem & 3;
    int d = dblk * 256 + t;

    float A2[16], wdt[16];
    const float* ap = Alog + (size_t)d * NST;
    const float* wp = dtw + (size_t)d * NST;
    #pragma unroll
    for (int n = 0; n < 16; n++) { A2[n] = -__expf(ap[n]) * LOG2E; wdt[n] = wp[n]; }
    float bdt = dtb[d];
    // A[n] = -(n+1) structure check (reference: A_log = log(tile(1..16)))
    bool fast = true;
    #pragma unroll
    for (int n = 0; n < 16; n++)
        fast = fast && (fabsf(A2[n] - (n + 1) * A2[0]) < 1e-3f);

    float h[16] = {0,0,0,0,0,0,0,0,0,0,0,0,0,0,0,0};
    float S = 0.0f;

    auto body = [&](auto FC) {
        constexpr bool F = decltype(FC)::value;
        for (int s = 0; s < TC; s++) {
            int q = c * TC + s;
            int l = dir ? (SEQ - 1 - q) : q;
            size_t row = (size_t)b * SEQ + l;
            const float* dr = dbl + row * 48;
            float dl[16], B[16];
            #pragma unroll
            for (int n = 0; n < 16; n += 4) {
                *(float4*)&dl[n] = *(const float4*)(dr + n);
                *(float4*)&B[n]  = *(const float4*)(dr + 16 + n);
            }
            float u = bf2f(xcp[row * 2048 + d]) + bf2f(xcp[row * 2048 + D_INNER + d]);
            float acc = bdt;
            #pragma unroll
            for (int n = 0; n < 16; n++) acc += dl[n] * wdt[n];
            float dt = (acc > 20.0f) ? acc : __logf(1.0f + __expf(acc));
            float dtu = dt * u;
            S += dt;
            float dA[16];
            if (F) {
                dA_pow(exp2f(A2[0] * dt), dA);
            } else {
                #pragma unroll
                for (int n = 0; n < 16; n++) dA[n] = exp2f(A2[n] * dt);
            }
            #pragma unroll
            for (int n = 0; n < 16; n++)
                h[n] = h[n] * dA[n] + dtu * B[n];
        }
    };
    if (fast) body(TrueT{}); else body(FalseT{});

    size_t NCH = (size_t)nb * 16384;
    size_t base = (size_t)c * NCH + ((size_t)b * 1024 + d) * 16;
    float Pv[16];
    if (fast) {
        dA_pow(exp2f(A2[0] * S), Pv);
    } else {
        #pragma unroll
        for (int n = 0; n < 16; n++) Pv[n] = exp2f(A2[n] * S);
    }
    #pragma unroll
    for (int n = 0; n < 16; n += 4) {
        *(float4*)&H[base + n] = *(float4*)&h[n];
        *(float4*)&P[base + n] = *(float4*)&Pv[n];
    }
}

// ------- scan phase 2: combine chunk states; H repurposed as h_in --------
__global__ __launch_bounds__(256) void scan_p2(const float* __restrict__ P,
                                               float* __restrict__ H,
                                               int NCH, int NC) {
    size_t chain = (size_t)blockIdx.x * 256 + threadIdx.x;
    float h = 0.0f;
    for (int c = 0; c < NC; c++) {
        size_t i = (size_t)c * NCH + chain;
        float Hc = H[i], Pc = P[i];
        H[i] = h;
        h = Hc + Pc * h;
    }
}

// ---- scan phase 3: recurrence + silu(z) + y -> split-bf16 pair ----------
__global__ __launch_bounds__(256) void scan_p3(const u16* __restrict__ xcp,
                                               const float* __restrict__ dbl,
                                               const float* __restrict__ dtw,
                                               const float* __restrict__ dtb,
                                               float* __restrict__ xz,
                                               const float* __restrict__ Alog,
                                               const float* __restrict__ Dp,
                                               const float* __restrict__ hin,
                                               int nb, int TC, int dir) {
    int t = threadIdx.x;
    int nblk4 = nb * 4;
    int c = blockIdx.x / nblk4;
    int rem = blockIdx.x - c * nblk4;
    int b = rem >> 2, dblk = rem & 3;
    int d = dblk * 256 + t;

    float A2[16], wdt[16];
    const float* ap = Alog + (size_t)d * NST;
    const float* wp = dtw + (size_t)d * NST;
    #pragma unroll
    for (int n = 0; n < 16; n++) { A2[n] = -__expf(ap[n]) * LOG2E; wdt[n] = wp[n]; }
    float bdt = dtb[d];
    float Dd = Dp[d];
    bool fast = true;
    #pragma unroll
    for (int n = 0; n < 16; n++)
        fast = fast && (fabsf(A2[n] - (n + 1) * A2[0]) < 1e-3f);

    size_t NCH = (size_t)nb * 16384;
    size_t base = (size_t)c * NCH + ((size_t)b * 1024 + d) * 16;
    float h[16];
    #pragma unroll
    for (int n = 0; n < 16; n += 4)
        *(float4*)&h[n] = *(const float4*)&hin[base + n];

    auto body = [&](auto FC) {
        constexpr bool F = decltype(FC)::value;
        for (int s = 0; s < TC; s++) {
            int q = c * TC + s;
            int l = dir ? (SEQ - 1 - q) : q;
            size_t row = (size_t)b * SEQ + l;
            const float* dr = dbl + row * 48;
            float dl[16], B[16], Cv[16];
            #pragma unroll
            for (int n = 0; n < 16; n += 4) {
                *(float4*)&dl[n] = *(const float4*)(dr + n);
                *(float4*)&B[n]  = *(const float4*)(dr + 16 + n);
                *(float4*)&Cv[n] = *(const float4*)(dr + 32 + n);
            }
            float u = bf2f(xcp[row * 2048 + d]) + bf2f(xcp[row * 2048 + D_INNER + d]);
            float acc = bdt;
            #pragma unroll
            for (int n = 0; n < 16; n++) acc += dl[n] * wdt[n];
            float dt = (acc > 20.0f) ? acc : __logf(1.0f + __expf(acc));
            float dtu = dt * u;
            float dA[16];
            if (F) {
                dA_pow(exp2f(A2[0] * dt), dA);
            } else {
                #pragma unroll
                for (int n = 0; n < 16; n++) dA[n] = exp2f(A2[n] * dt);
            }
            #pragma unroll
            for (int n = 0; n < 16; n++)
                h[n] = h[n] * dA[n] + dtu * B[n];

            float p0 = h[0]*Cv[0] + h[1]*Cv[1] + h[2]*Cv[2] + h[3]*Cv[3];
            float p1 = h[4]*Cv[4] + h[5]*Cv[5] + h[6]*Cv[6] + h[7]*Cv[7];
            float p2 = h[8]*Cv[8] + h[9]*Cv[9] + h[10]*Cv[10] + h[11]*Cv[11];
            float p3 = h[12]*Cv[12] + h[13]*Cv[13] + h[14]*Cv[14] + h[15]*Cv[15];

            float z = xz[row * (2 * D_INNER) + D_INNER + d];
            float g = z / (1.0f + __expf(-z));
            float y = ((p0 + p1) + (p2 + p3) + u * Dd) * g;

            u16* yp = (u16*)(xz + row * (2 * D_INNER));
            u16 hi = f2bf(y);
            yp[d] = hi;
            yp[D_INNER + d] = f2bf(y - bf2f(hi));
        }
    };
    if (fast) body(TrueT{}); else body(FalseT{});
}

// ---------------- host launch --------------------------------------------
extern "C" void kernel_launch(void* const* d_in, const int* in_sizes, int n_in,
                              void* d_out, int out_size, void* d_ws, size_t ws_size,
                              hipStream_t stream) {
    const float* input = (const float*)d_in[0];
    float* out = (float*)d_out;

    const size_t phfix = (size_t)2 * 256 * 16384 * 4;                 // 33.6 MB
    const size_t perb  = (size_t)2048 * (256 + 2048 + 1024 + 48) * 4; // 27.7 MB
    const size_t wspl  = (size_t)(2048 * 512 + 256 * 2048 + 48 * 2048) * 2;
    int nb = 4;                       // out_proj partials (R*4096 B) fit P+H
    while (nb > 1 && phfix + (size_t)nb * perb + wspl > ws_size) nb >>= 1;
    const int NC = 256 / nb;
    const int TC = SEQ / NC;
    const int R = nb * SEQ;
    const int NCH = nb * 16384;

    float* P    = (float*)d_ws;        // xproj partials / out_proj partials / scan P
    float* H    = P + (size_t)256 * 16384;
    float* xnf  = H + (size_t)256 * 16384;
    float* xz   = xnf + (size_t)R * D_MODEL;
    float* xcyf = xz  + (size_t)R * 2 * D_INNER;
    float* dbl  = xcyf + (size_t)R * D_INNER;
    u16*  winp  = (u16*)(dbl + (size_t)R * 48);
    u16*  woutp = winp + (size_t)2048 * 512;
    u16*  xpp   = woutp + (size_t)256 * 2048;
    u16*  xnp   = (u16*)xnf;
    u16*  xcp   = (u16*)xcyf;

    for (int dir = 0; dir < 2; dir++) {
        int o = 1 + dir * 10;
        const float* nw   = (const float*)d_in[o + 0];
        const float* win  = (const float*)d_in[o + 1];
        const float* cw   = (const float*)d_in[o + 2];
        const float* cb   = (const float*)d_in[o + 3];
        const float* xp   = (const float*)d_in[o + 4];
        const float* dtw  = (const float*)d_in[o + 5];
        const float* dtbv = (const float*)d_in[o + 6];
        const float* Alog = (const float*)d_in[o + 7];
        const float* Dp   = (const float*)d_in[o + 8];
        const float* wout = (const float*)d_in[o + 9];

        wsplit_k<<<2048 * 256 / 256, 256, 0, stream>>>(win, winp, D_MODEL);
        wsplit_k<<<256 * 1024 / 256, 256, 0, stream>>>(wout, woutp, D_INNER);
        wsplit_k<<<48 * 1024 / 256, 256, 0, stream>>>(xp, xpp, D_INNER);

        for (int b0 = 0; b0 < 8; b0 += nb) {
            const float* xin = input + (size_t)b0 * SEQ * D_MODEL;
            float* cout = out + (size_t)b0 * SEQ * 2 * D_MODEL;

            rmsnorm_k<<<R, 256, 0, stream>>>(xin, nw, xnp);
            gemm_mfma<<<dim3(R / 128, 16, 1), 256, 0, stream>>>(
                xnp, 512, winp, 512, xz, 2 * D_INNER, D_MODEL, 3 * D_MODEL, 0,
                2 * D_INNER);
            conv_silu_k<<<R, 256, 0, stream>>>(xz, cw, cb, xcp, dir);
            gemm_mfma<<<dim3(R / 128, 1, 8), 256, 0, stream>>>(
                xcp, 2048, xpp, 2048, P, 48, D_INNER, 384, (size_t)R * 48, 48);
            reduce_dbl_k<<<R * 48 / 256, 256, 0, stream>>>(P, dbl, (size_t)R * 48);
            scan_p1<<<NC * nb * 4, 256, 0, stream>>>(
                xcp, dbl, dtw, dtbv, Alog, P, H, nb, TC, dir);
            scan_p2<<<NCH / 256, 256, 0, stream>>>(P, H, NCH, NC);
            scan_p3<<<NC * nb * 4, 256, 0, stream>>>(
                xcp, dbl, dtw, dtbv, xz, Alog, Dp, H, nb, TC, dir);
            gemm_mfma<<<dim3(R / 128, 2, 4), 256, 0, stream>>>(
                (const u16*)xz, 4096, woutp, 2048, P, 256, D_INNER, 768,
                (size_t)R * 256, 256);
            reduce_out_k<<<R * 64 / 256, 256, 0, stream>>>(
                P, xin, cout, R, dir * D_MODEL);
        }
    }
}

// Round 10
// 1015.564 us; speedup vs baseline: 5.5621x; 1.0140x over previous
//
#include <hip/hip_runtime.h>

typedef unsigned short u16;
typedef __bf16 bf16x8 __attribute__((ext_vector_type(8)));
typedef float f32x4 __attribute__((ext_vector_type(4)));

#define D_MODEL 256
#define D_INNER 1024
#define NST     16
#define SEQ     2048
#define LOG2E   1.4426950408889634f

struct TrueT  { static constexpr bool value = true;  };
struct FalseT { static constexpr bool value = false; };

static __device__ __forceinline__ float bf2f(u16 u) {
    union { float f; unsigned v; } x; x.v = ((unsigned)u) << 16; return x.f;
}
static __device__ __forceinline__ u16 f2bf(float f) {
    union { float f; unsigned u; } x; x.f = f;
    unsigned r = 0x7FFF + ((x.u >> 16) & 1);
    return (u16)((x.u + r) >> 16);
}

// dA[n] = e1^(n+1), n=0..15, via binary decomposition (16 muls, depth ~5)
static __device__ __forceinline__ void dA_pow(float e1, float* dA) {
    float e2 = e1 * e1, e3 = e2 * e1, e4 = e2 * e2;
    float e8 = e4 * e4, e12 = e8 * e4;
    dA[0] = e1;       dA[1] = e2;       dA[2] = e3;       dA[3] = e4;
    dA[4] = e4 * e1;  dA[5] = e4 * e2;  dA[6] = e4 * e3;  dA[7] = e8;
    dA[8] = e8 * e1;  dA[9] = e8 * e2;  dA[10] = e8 * e3; dA[11] = e12;
    dA[12] = e12 * e1; dA[13] = e12 * e2; dA[14] = e12 * e3; dA[15] = e8 * e8;
}

// ---- RMSNorm -> split-bf16 pair output: row = [256 hi | 256 lo] u16 ----
__global__ __launch_bounds__(256) void rmsnorm_k(const float* __restrict__ x,
                                                 const float* __restrict__ w,
                                                 u16* __restrict__ xnp) {
    int row = blockIdx.x, t = threadIdx.x;
    float v = x[(size_t)row * D_MODEL + t];
    float s = v * v;
    #pragma unroll
    for (int o = 32; o; o >>= 1) s += __shfl_xor(s, o, 64);
    __shared__ float red[4];
    if ((t & 63) == 0) red[t >> 6] = s;
    __syncthreads();
    float tot = red[0] + red[1] + red[2] + red[3];
    float scale = rsqrtf(tot * (1.0f / D_MODEL) + 1e-5f);
    float xv = v * scale * w[t];
    u16 hi = f2bf(xv);
    u16 lo = f2bf(xv - bf2f(hi));
    xnp[(size_t)row * 512 + t] = hi;
    xnp[(size_t)row * 512 + 256 + t] = lo;
}

// ---- weight split: src[N*K] f32 -> dst[N][2K] bf16 (hi | lo) -----------
__global__ __launch_bounds__(256) void wsplit_k(const float* __restrict__ src,
                                                u16* __restrict__ dst, int K) {
    int i = blockIdx.x * 256 + threadIdx.x;
    int n = i / K, k = i - n * K;
    float v = src[i];
    u16 hi = f2bf(v);
    u16 lo = f2bf(v - bf2f(hi));
    dst[(size_t)n * 2 * K + k] = hi;
    dst[(size_t)n * 2 * K + K + k] = lo;
}

// ---- split-bf16 MFMA GEMM over augmented K' = 3*KL (R8 proven version) --
// Terms: t=0: Ah*Wh, t=1: Ah*Wl, t=2: Al*Wh. Tile 128x128, BK=64, 4 waves.
__global__ __launch_bounds__(256) void gemm_mfma(const u16* __restrict__ Ap, int lda,
                                                 const u16* __restrict__ Wp, int ldw,
                                                 float* __restrict__ C, int ldc,
                                                 int KL, int kslice, size_t zstride,
                                                 int Nreal) {
    __shared__ u16 As[128][72];
    __shared__ u16 Ws[128][72];
    const int m0 = blockIdx.x * 128, n0 = blockIdx.y * 128;
    const int tid = threadIdx.x;
    const int wave = tid >> 6, lane = tid & 63;
    const int wm = (wave >> 1) * 64, wn = (wave & 1) * 64;
    const int lm = lane & 15, quad = lane >> 4;
    const int srow = tid >> 3, skk = (tid & 7) * 8;

    f32x4 acc[4][4] = {};

    const int kb0 = blockIdx.z * kslice;
    for (int k0 = kb0; k0 < kb0 + kslice; k0 += 64) {
        int t = k0 / KL;
        int ko = k0 - t * KL;
        int ka = ko + (t == 2 ? KL : 0);
        int kw = ko + (t == 1 ? KL : 0);
        #pragma unroll
        for (int p = 0; p < 4; p++) {
            int row = p * 32 + srow;
            *(uint4*)&As[row][skk] =
                *(const uint4*)(Ap + (size_t)(m0 + row) * lda + ka + skk);
            uint4 wv = {0u, 0u, 0u, 0u};
            if (n0 + row < Nreal)
                wv = *(const uint4*)(Wp + (size_t)(n0 + row) * ldw + kw + skk);
            *(uint4*)&Ws[row][skk] = wv;
        }
        __syncthreads();
        #pragma unroll
        for (int kk = 0; kk < 2; kk++) {
            bf16x8 af[4], bv[4];
            #pragma unroll
            for (int i = 0; i < 4; i++)
                af[i] = *(const bf16x8*)&As[wm + i * 16 + lm][kk * 32 + quad * 8];
            #pragma unroll
            for (int j = 0; j < 4; j++)
                bv[j] = *(const bf16x8*)&Ws[wn + j * 16 + lm][kk * 32 + quad * 8];
            #pragma unroll
            for (int i = 0; i < 4; i++)
                #pragma unroll
                for (int j = 0; j < 4; j++)
                    acc[i][j] = __builtin_amdgcn_mfma_f32_16x16x32_bf16(
                        af[i], bv[j], acc[i][j], 0, 0, 0);
        }
        __syncthreads();
    }

    float* Cz = C + zstride * blockIdx.z;
    #pragma unroll
    for (int i = 0; i < 4; i++)
        #pragma unroll
        for (int j = 0; j < 4; j++)
            #pragma unroll
            for (int r = 0; r < 4; r++) {
                int mrow = m0 + wm + i * 16 + quad * 4 + r;   // C/D: row=quad*4+reg
                int ncol = n0 + wn + j * 16 + lm;             //      col=lane&15
                if (ncol < Nreal)
                    Cz[(size_t)mrow * ldc + ncol] = acc[i][j][r];
            }
}

// ------ reduce 8 x_proj partials -> dbl[R*48] -----------------------------
__global__ __launch_bounds__(256) void reduce_dbl_k(const float* __restrict__ pbuf,
                                                    float* __restrict__ dbl,
                                                    size_t RS) {
    size_t e = (size_t)blockIdx.x * 256 + threadIdx.x;
    float v = 0.0f;
    #pragma unroll
    for (int z = 0; z < 8; z++) v += pbuf[z * RS + e];
    dbl[e] = v;
}

// ------ reduce 4 out_proj partials + residual -> out[m, coff + n] ---------
__global__ __launch_bounds__(256) void reduce_out_k(const float* __restrict__ pbuf,
                                                    const float* __restrict__ res,
                                                    float* __restrict__ out,
                                                    int M, int coff) {
    int idx = blockIdx.x * 256 + threadIdx.x;
    int m = idx >> 6, n4 = (idx & 63) * 4;
    size_t e = (size_t)m * 256 + n4;
    size_t stride = (size_t)M * 256;
    float4 v = *(const float4*)(res + e);
    #pragma unroll
    for (int s = 0; s < 4; s++) {
        float4 p = *(const float4*)(pbuf + s * stride + e);
        v.x += p.x; v.y += p.y; v.z += p.z; v.w += p.w;
    }
    *(float4*)(out + (size_t)m * 512 + coff + n4) = v;
}

// ---- depthwise causal conv + SiLU; out = split-bf16 pair ----------------
__global__ __launch_bounds__(256) void conv_silu_k(const float* __restrict__ xz,
                                                   const float* __restrict__ cw,
                                                   const float* __restrict__ cb,
                                                   u16* __restrict__ xcp, int dir) {
    int bx = blockIdx.x;
    int dgrp = bx & 3;
    int rowgrp = bx >> 2;
    int l0 = (rowgrp & (SEQ / 4 - 1)) * 4;
    int b = rowgrp >> 9;
    int d = dgrp * 256 + threadIdx.x;

    int base = dir ? l0 : (l0 - 3);
    float x[7];
    #pragma unroll
    for (int i = 0; i < 7; i++) {
        int lr = base + i;
        x[i] = (lr >= 0 && lr < SEQ)
             ? xz[((size_t)b * SEQ + lr) * (2 * D_INNER) + d] : 0.0f;
    }
    float w0 = cw[d * 4 + 0], w1 = cw[d * 4 + 1];
    float w2 = cw[d * 4 + 2], w3 = cw[d * 4 + 3];
    float bias = cb[d];

    #pragma unroll
    for (int li = 0; li < 4; li++) {
        float acc;
        if (dir == 0)
            acc = bias + w0 * x[li] + w1 * x[li + 1] + w2 * x[li + 2] + w3 * x[li + 3];
        else
            acc = bias + w3 * x[li] + w2 * x[li + 1] + w1 * x[li + 2] + w0 * x[li + 3];
        float s = acc / (1.0f + __expf(-acc));
        u16 hi = f2bf(s);
        u16 lo = f2bf(s - bf2f(hi));
        size_t row = (size_t)b * SEQ + l0 + li;
        xcp[row * 2048 + d] = hi;
        xcp[row * 2048 + D_INNER + d] = lo;
    }
}

// ---- scan phase 1: per-chunk H (h_in=0) and P; dbl staged in LDS --------
__global__ __launch_bounds__(256) void scan_p1(const u16* __restrict__ xcp,
                                               const float* __restrict__ dbl,
                                               const float* __restrict__ dtw,
                                               const float* __restrict__ dtb,
                                               const float* __restrict__ Alog,
                                               float* __restrict__ P,
                                               float* __restrict__ H,
                                               int nb, int TC, int dir) {
    __shared__ float sdbl[32 * 48];            // TC <= 32
    int t = threadIdx.x;
    int nblk4 = nb * 4;
    int c = blockIdx.x / nblk4;
    int rem = blockIdx.x - c * nblk4;
    int b = rem >> 2, dblk = rem & 3;
    int d = dblk * 256 + t;

    // stage this chunk's dbl rows (memory order) into LDS
    int lbase = dir ? (SEQ - (c + 1) * TC) : (c * TC);
    {
        const float* src = dbl + ((size_t)b * SEQ + lbase) * 48;
        int nf4 = TC * 12;
        for (int i = t; i < nf4; i += 256)
            *(float4*)&sdbl[i * 4] = *(const float4*)(src + i * 4);
    }

    float A2[16], wdt[16];
    const float* ap = Alog + (size_t)d * NST;
    const float* wp = dtw + (size_t)d * NST;
    #pragma unroll
    for (int n = 0; n < 16; n++) { A2[n] = -__expf(ap[n]) * LOG2E; wdt[n] = wp[n]; }
    float bdt = dtb[d];
    bool fast = true;
    #pragma unroll
    for (int n = 0; n < 16; n++)
        fast = fast && (fabsf(A2[n] - (n + 1) * A2[0]) < 1e-3f);

    float h[16] = {0,0,0,0,0,0,0,0,0,0,0,0,0,0,0,0};
    float S = 0.0f;

    int lstep = dir ? -1 : 1;
    int l0 = dir ? (lbase + TC - 1) : lbase;
    const u16* up = xcp + ((size_t)b * SEQ + l0) * 2048 + d;
    ptrdiff_t ups = (ptrdiff_t)lstep * 2048;
    const float* dr = sdbl + (dir ? (TC - 1) * 48 : 0);
    ptrdiff_t drs = (ptrdiff_t)lstep * 48;

    __syncthreads();

    auto body = [&](auto FC) {
        constexpr bool F = decltype(FC)::value;
        #pragma unroll 2
        for (int s = 0; s < TC; s++) {
            float dl[16], B[16];
            #pragma unroll
            for (int n = 0; n < 16; n += 4) {
                *(float4*)&dl[n] = *(const float4*)(dr + n);
                *(float4*)&B[n]  = *(const float4*)(dr + 16 + n);
            }
            float u = bf2f(up[0]) + bf2f(up[D_INNER]);
            float acc = bdt;
            #pragma unroll
            for (int n = 0; n < 16; n++) acc += dl[n] * wdt[n];
            float dt = (acc > 20.0f) ? acc : __logf(1.0f + __expf(acc));
            float dtu = dt * u;
            S += dt;
            float dA[16];
            if (F) {
                dA_pow(exp2f(A2[0] * dt), dA);
            } else {
                #pragma unroll
                for (int n = 0; n < 16; n++) dA[n] = exp2f(A2[n] * dt);
            }
            #pragma unroll
            for (int n = 0; n < 16; n++)
                h[n] = h[n] * dA[n] + dtu * B[n];
            dr += drs; up += ups;
        }
    };
    if (fast) body(TrueT{}); else body(FalseT{});

    size_t NCH = (size_t)nb * 16384;
    size_t base = (size_t)c * NCH + ((size_t)b * 1024 + d) * 16;
    float Pv[16];
    if (fast) {
        dA_pow(exp2f(A2[0] * S), Pv);
    } else {
        #pragma unroll
        for (int n = 0; n < 16; n++) Pv[n] = exp2f(A2[n] * S);
    }
    #pragma unroll
    for (int n = 0; n < 16; n += 4) {
        *(float4*)&H[base + n] = *(float4*)&h[n];
        *(float4*)&P[base + n] = *(float4*)&Pv[n];
    }
}

// ------- scan phase 2: combine chunk states; H repurposed as h_in --------
__global__ __launch_bounds__(256) void scan_p2(const float* __restrict__ P,
                                               float* __restrict__ H,
                                               int NCH, int NC) {
    size_t chain = (size_t)blockIdx.x * 256 + threadIdx.x;
    float h = 0.0f;
    for (int c = 0; c < NC; c++) {
        size_t i = (size_t)c * NCH + chain;
        float Hc = H[i], Pc = P[i];
        H[i] = h;
        h = Hc + Pc * h;
    }
}

// ---- scan phase 3: recurrence + silu(z) + y pair; dbl staged in LDS -----
__global__ __launch_bounds__(256) void scan_p3(const u16* __restrict__ xcp,
                                               const float* __restrict__ dbl,
                                               const float* __restrict__ dtw,
                                               const float* __restrict__ dtb,
                                               float* __restrict__ xz,
                                               const float* __restrict__ Alog,
                                               const float* __restrict__ Dp,
                                               const float* __restrict__ hin,
                                               int nb, int TC, int dir) {
    __shared__ float sdbl[32 * 48];
    int t = threadIdx.x;
    int nblk4 = nb * 4;
    int c = blockIdx.x / nblk4;
    int rem = blockIdx.x - c * nblk4;
    int b = rem >> 2, dblk = rem & 3;
    int d = dblk * 256 + t;

    int lbase = dir ? (SEQ - (c + 1) * TC) : (c * TC);
    {
        const float* src = dbl + ((size_t)b * SEQ + lbase) * 48;
        int nf4 = TC * 12;
        for (int i = t; i < nf4; i += 256)
            *(float4*)&sdbl[i * 4] = *(const float4*)(src + i * 4);
    }

    float A2[16], wdt[16];
    const float* ap = Alog + (size_t)d * NST;
    const float* wp = dtw + (size_t)d * NST;
    #pragma unroll
    for (int n = 0; n < 16; n++) { A2[n] = -__expf(ap[n]) * LOG2E; wdt[n] = wp[n]; }
    float bdt = dtb[d];
    float Dd = Dp[d];
    bool fast = true;
    #pragma unroll
    for (int n = 0; n < 16; n++)
        fast = fast && (fabsf(A2[n] - (n + 1) * A2[0]) < 1e-3f);

    size_t NCH = (size_t)nb * 16384;
    size_t base = (size_t)c * NCH + ((size_t)b * 1024 + d) * 16;
    float h[16];
    #pragma unroll
    for (int n = 0; n < 16; n += 4)
        *(float4*)&h[n] = *(const float4*)&hin[base + n];

    int lstep = dir ? -1 : 1;
    int l0 = dir ? (lbase + TC - 1) : lbase;
    size_t row0 = (size_t)b * SEQ + l0;
    const u16* up = xcp + row0 * 2048 + d;
    const float* zp = xz + row0 * 2048 + D_INNER + d;
    u16* yp = (u16*)(xz + row0 * 2048) + d;
    ptrdiff_t ups = (ptrdiff_t)lstep * 2048;
    ptrdiff_t zps = (ptrdiff_t)lstep * 2048;
    ptrdiff_t yps = (ptrdiff_t)lstep * 4096;   // u16 pitch of a 2048-float row
    const float* dr = sdbl + (dir ? (TC - 1) * 48 : 0);
    ptrdiff_t drs = (ptrdiff_t)lstep * 48;

    __syncthreads();

    auto body = [&](auto FC) {
        constexpr bool F = decltype(FC)::value;
        #pragma unroll 2
        for (int s = 0; s < TC; s++) {
            float dl[16], B[16], Cv[16];
            #pragma unroll
            for (int n = 0; n < 16; n += 4) {
                *(float4*)&dl[n] = *(const float4*)(dr + n);
                *(float4*)&B[n]  = *(const float4*)(dr + 16 + n);
                *(float4*)&Cv[n] = *(const float4*)(dr + 32 + n);
            }
            float u = bf2f(up[0]) + bf2f(up[D_INNER]);
            float acc = bdt;
            #pragma unroll
            for (int n = 0; n < 16; n++) acc += dl[n] * wdt[n];
            float dt = (acc > 20.0f) ? acc : __logf(1.0f + __expf(acc));
            float dtu = dt * u;
            float dA[16];
            if (F) {
                dA_pow(exp2f(A2[0] * dt), dA);
            } else {
                #pragma unroll
                for (int n = 0; n < 16; n++) dA[n] = exp2f(A2[n] * dt);
            }
            #pragma unroll
            for (int n = 0; n < 16; n++)
                h[n] = h[n] * dA[n] + dtu * B[n];

            float p0 = h[0]*Cv[0] + h[1]*Cv[1] + h[2]*Cv[2] + h[3]*Cv[3];
            float p1 = h[4]*Cv[4] + h[5]*Cv[5] + h[6]*Cv[6] + h[7]*Cv[7];
            float p2 = h[8]*Cv[8] + h[9]*Cv[9] + h[10]*Cv[10] + h[11]*Cv[11];
            float p3 = h[12]*Cv[12] + h[13]*Cv[13] + h[14]*Cv[14] + h[15]*Cv[15];

            float z = *zp;
            float g = z / (1.0f + __expf(-z));
            float y = ((p0 + p1) + (p2 + p3) + u * Dd) * g;

            u16 hi = f2bf(y);
            yp[0] = hi;
            yp[D_INNER] = f2bf(y - bf2f(hi));

            dr += drs; up += ups; zp += zps; yp += yps;
        }
    };
    if (fast) body(TrueT{}); else body(FalseT{});
}

// ---------------- host launch --------------------------------------------
extern "C" void kernel_launch(void* const* d_in, const int* in_sizes, int n_in,
                              void* d_out, int out_size, void* d_ws, size_t ws_size,
                              hipStream_t stream) {
    const float* input = (const float*)d_in[0];
    float* out = (float*)d_out;

    const size_t phfix = (size_t)2 * 256 * 16384 * 4;                 // 33.6 MB
    const size_t perb  = (size_t)2048 * (256 + 2048 + 1024 + 48) * 4; // 27.7 MB
    const size_t wspl  = (size_t)(2048 * 512 + 256 * 2048 + 48 * 2048) * 2;
    int nb = 4;                       // out_proj partials (R*4096 B) fit P+H
    while (nb > 1 && phfix + (size_t)nb * perb + wspl > ws_size) nb >>= 1;
    const int NC = 256 / nb;
    const int TC = SEQ / NC;
    const int R = nb * SEQ;
    const int NCH = nb * 16384;

    float* P    = (float*)d_ws;        // xproj partials / out_proj partials / scan P
    float* H    = P + (size_t)256 * 16384;
    float* xnf  = H + (size_t)256 * 16384;
    float* xz   = xnf + (size_t)R * D_MODEL;
    float* xcyf = xz  + (size_t)R * 2 * D_INNER;
    float* dbl  = xcyf + (size_t)R * D_INNER;
    u16*  winp  = (u16*)(dbl + (size_t)R * 48);
    u16*  woutp = winp + (size_t)2048 * 512;
    u16*  xpp   = woutp + (size_t)256 * 2048;
    u16*  xnp   = (u16*)xnf;
    u16*  xcp   = (u16*)xcyf;

    for (int dir = 0; dir < 2; dir++) {
        int o = 1 + dir * 10;
        const float* nw   = (const float*)d_in[o + 0];
        const float* win  = (const float*)d_in[o + 1];
        const float* cw   = (const float*)d_in[o + 2];
        const float* cb   = (const float*)d_in[o + 3];
        const float* xp   = (const float*)d_in[o + 4];
        const float* dtw  = (const float*)d_in[o + 5];
        const float* dtbv = (const float*)d_in[o + 6];
        const float* Alog = (const float*)d_in[o + 7];
        const float* Dp   = (const float*)d_in[o + 8];
        const float* wout = (const float*)d_in[o + 9];

        wsplit_k<<<2048 * 256 / 256, 256, 0, stream>>>(win, winp, D_MODEL);
        wsplit_k<<<256 * 1024 / 256, 256, 0, stream>>>(wout, woutp, D_INNER);
        wsplit_k<<<48 * 1024 / 256, 256, 0, stream>>>(xp, xpp, D_INNER);

        for (int b0 = 0; b0 < 8; b0 += nb) {
            const float* xin = input + (size_t)b0 * SEQ * D_MODEL;
            float* cout = out + (size_t)b0 * SEQ * 2 * D_MODEL;

            rmsnorm_k<<<R, 256, 0, stream>>>(xin, nw, xnp);
            // in_proj: xz[R,2048] = xn * win^T, K'=768
            gemm_mfma<<<dim3(R / 128, 16, 1), 256, 0, stream>>>(
                xnp, 512, winp, 512, xz, 2 * D_INNER, D_MODEL, 3 * D_MODEL, 0,
                2 * D_INNER);
            conv_silu_k<<<R, 256, 0, stream>>>(xz, cw, cb, xcp, dir);
            // x_proj: partials[8][R,48] = xc * xp^T, K'=3072, split-K=8
            gemm_mfma<<<dim3(R / 128, 1, 8), 256, 0, stream>>>(
                xcp, 2048, xpp, 2048, P, 48, D_INNER, 384, (size_t)R * 48, 48);
            reduce_dbl_k<<<R * 48 / 256, 256, 0, stream>>>(P, dbl, (size_t)R * 48);
            scan_p1<<<NC * nb * 4, 256, 0, stream>>>(
                xcp, dbl, dtw, dtbv, Alog, P, H, nb, TC, dir);
            scan_p2<<<NCH / 256, 256, 0, stream>>>(P, H, NCH, NC);
            scan_p3<<<NC * nb * 4, 256, 0, stream>>>(
                xcp, dbl, dtw, dtbv, xz, Alog, Dp, H, nb, TC, dir);
            // out_proj: y_pair * wout^T, K'=3072, split-K=4
            gemm_mfma<<<dim3(R / 128, 2, 4), 256, 0, stream>>>(
                (const u16*)xz, 4096, woutp, 2048, P, 256, D_INNER, 768,
                (size_t)R * 256, 256);
            reduce_out_k<<<R * 64 / 256, 256, 0, stream>>>(
                P, xin, cout, R, dir * D_MODEL);
        }
    }
}